// Round 4
// baseline (2145.072 us; speedup 1.0000x reference)
//
#include <hip/hip_runtime.h>
#include <math.h>

#define NN 50000
#define TT 12
#define EE 1600000
#define FF 16
#define HH 128
#define CHK 4096     // edges per chunk (level-1 histogram / scatter staging)
#define NCH 391      // ceil(EE/CHK)
#define BKT 128      // nodes per bin
#define NBINS 391    // ceil(NN/BKT) -> covers 50048
#define CAP 6144     // max edges per bin segment (mean 4096, sigma 64)
#define RP 50016     // rowptr stride per t (>= NN+1)
#define CGB 782      // ceil(NN/64) cell blocks
#define AH_STR 136   // h-part A LDS stride (halves): 272B rows
#define AX_STR 40    // x-part A LDS stride (halves)
#define HC_STR 136   // committed-h LDS stride (halves)
#define BKROW 160    // BcatT row stride in halves: [h 0..127 | x 128..143 | zero 144..159]

typedef _Float16 half8_t __attribute__((ext_vector_type(8)));
typedef float floatx4 __attribute__((ext_vector_type(4)));

__device__ __forceinline__ float h16_to_f(unsigned short u) {
    _Float16 h; __builtin_memcpy(&h, &u, 2); return (float)h;
}
__device__ __forceinline__ unsigned short f_to_h16(float f) {
    _Float16 h = (_Float16)f; unsigned short u; __builtin_memcpy(&u, &h, 2); return u;
}
__device__ __forceinline__ float fsig(float x) {
    return 1.0f / (1.0f + exp2f(-1.44269504f * x));
}
__device__ __forceinline__ float ftanh(float x) {
    return 2.0f / (1.0f + exp2f(-2.88539009f * x)) - 1.0f;
}

// ---------------------------------------------------------------------------
// P0: detect mask dtype from byte pattern (uint8 / int32 / float32).
__global__ void detect_mask(const unsigned char* __restrict__ m, int* __restrict__ flag) {
    __shared__ int cnt[2];
    if (threadIdx.x < 2) cnt[threadIdx.x] = 0;
    __syncthreads();
    int a = 0, b = 0;
    for (int base = 0; base < 4096; base += 256) {
        int idx = base + threadIdx.x;
        unsigned char v = m[idx];
        int r = idx & 3;
        if (v) { if (r == 0) a++; else if (r == 1) b++; }
    }
    atomicAdd(&cnt[0], a);
    atomicAdd(&cnt[1], b);
    __syncthreads();
    if (threadIdx.x == 0) flag[0] = cnt[1] > 0 ? 0 : (cnt[0] > 0 ? 1 : 2);
}

// P1: hm[t][n] = mask & seen-before, mc[t][n] = mask
__global__ void build_masks(const void* __restrict__ mask, const int* __restrict__ flag,
                            unsigned char* __restrict__ hm, unsigned char* __restrict__ mc) {
    int n = blockIdx.x * 256 + threadIdx.x;
    if (n >= NN) return;
    int mode = flag[0];
    bool seen = false;
    for (int t = 0; t < TT; t++) {
        int idx = t * NN + n;
        bool m;
        if (mode == 0)      m = ((const unsigned char*)mask)[idx] != 0;
        else if (mode == 1) m = ((const int*)mask)[idx] != 0;
        else                m = ((const float*)mask)[idx] != 0.0f;
        hm[idx] = (m && seen) ? 1 : 0;
        mc[idx] = m ? 1 : 0;
        seen = seen || m;
    }
}

// ---------------------------------------------------------------------------
// S1: per-chunk histogram of dst bins (bin = dst>>7). layout [t][bin][chunk]
__global__ void hist_kernel(const int* __restrict__ ei, int* __restrict__ chunkHist) {
    __shared__ int h[NBINS + 1];
    int c = blockIdx.x, t = blockIdx.y, tid = threadIdx.x;
    for (int i = tid; i < NBINS; i += 256) h[i] = 0;
    __syncthreads();
    const int* dstp = ei + (size_t)(2 * t + 1) * EE;
    int e0 = c * CHK;
    for (int i = tid; i < CHK; i += 256) {
        int e = e0 + i;
        if (e < EE) atomicAdd(&h[dstp[e] >> 7], 1);
    }
    __syncthreads();
    for (int i = tid; i < NBINS; i += 256)
        chunkHist[((size_t)t * NBINS + i) * NCH + c] = h[i];
}

// S2: in-place exclusive scan of each t's [NBINS*NCH] array
__global__ void scan_kernel(int* __restrict__ buf) {
    __shared__ int ps[1024];
    const int L = NBINS * NCH;   // 152881
    const int PER = 150;         // 1024*150 >= L
    int t = blockIdx.x, tid = threadIdx.x;
    int* a = buf + (size_t)t * L;
    int i0 = tid * PER, i1 = min(i0 + PER, L);
    int s = 0;
    for (int i = i0; i < i1; i++) s += a[i];
    ps[tid] = s;
    __syncthreads();
    for (int off = 1; off < 1024; off <<= 1) {
        int v = (tid >= off) ? ps[tid - off] : 0;
        __syncthreads();
        ps[tid] += v;
        __syncthreads();
    }
    int base = (tid == 0) ? 0 : ps[tid - 1];
    for (int i = i0; i < i1; i++) { int v = a[i]; a[i] = base; base += v; }
}

// S3: LDS-staged scatter into bin-sorted order (batch of 6 t's).
// Record: uint2{src|dst<<16, w_f32}. Coalesced segment write-out.
__launch_bounds__(256)
__global__ void scatter_kernel(const int* __restrict__ ei, const float* __restrict__ ea,
                               const int* __restrict__ chunkOff, uint2* __restrict__ E2,
                               int batch) {
    __shared__ uint2 sorted[CHK];          // 32 KB
    __shared__ int cnt[NBINS];
    __shared__ int sA[NBINS], sB[NBINS];
    __shared__ int start[NBINS], gbase[NBINS];
    int c = blockIdx.x, y = blockIdx.y, tid = threadIdx.x;
    int t = batch * 6 + y;
    for (int i = tid; i < NBINS; i += 256) {
        cnt[i] = 0;
        gbase[i] = chunkOff[((size_t)t * NBINS + i) * NCH + c];
    }
    __syncthreads();
    const int* srcp = ei + (size_t)(2 * t) * EE;
    const int* dstp = ei + (size_t)(2 * t + 1) * EE;
    const float* wp = ea + (size_t)t * EE;
    int e0 = c * CHK;
    int m = min(CHK, EE - e0);
    uint2 rec[16];
    int rank[16];
#pragma unroll
    for (int k = 0; k < 16; k++) {
        int i = k * 256 + tid;
        rank[k] = -1;
        if (i < m) {
            int e = e0 + i;
            unsigned int s = (unsigned int)srcp[e];
            unsigned int d = (unsigned int)dstp[e];
            float wv = wp[e];
            rec[k].x = s | (d << 16);
            rec[k].y = __float_as_uint(wv);
            rank[k] = atomicAdd(&cnt[d >> 7], 1);
        }
    }
    __syncthreads();
    for (int i = tid; i < NBINS; i += 256) sA[i] = cnt[i];
    __syncthreads();
    int pp = 0;
    for (int off = 1; off < NBINS; off <<= 1) {
        if (pp == 0) {
            for (int i = tid; i < NBINS; i += 256)
                sB[i] = (i >= off) ? sA[i] + sA[i - off] : sA[i];
        } else {
            for (int i = tid; i < NBINS; i += 256)
                sA[i] = (i >= off) ? sB[i] + sB[i - off] : sB[i];
        }
        pp ^= 1;
        __syncthreads();
    }
    const int* inc = pp ? sB : sA;
    for (int i = tid; i < NBINS; i += 256) start[i] = inc[i] - cnt[i];
    __syncthreads();
#pragma unroll
    for (int k = 0; k < 16; k++) {
        if (rank[k] >= 0) {
            int b = rec[k].x >> 23;
            sorted[start[b] + rank[k]] = rec[k];
        }
    }
    __syncthreads();
    uint2* outp = E2 + (size_t)y * EE;
    for (int i = tid; i < m; i += 256) {
        uint2 r = sorted[i];
        int b = r.x >> 23;
        outp[gbase[b] + (i - start[b])] = r;
    }
}

// S4: per-bin counting sort -> compact CSR records (src u16 | w'=w*dinv[d] f16)
// + rowptr + dinv. Reads uint2 staging E2, writes 4B records to E1.
__launch_bounds__(256)
__global__ void sortbin_kernel(const uint2* __restrict__ E2, const int* __restrict__ chunkHist,
                               unsigned int* __restrict__ E1, int* __restrict__ rowptr,
                               float* __restrict__ dinvG, int batch) {
    __shared__ uint2 es[CAP];   // 48 KB
    __shared__ int cnt[BKT];
    __shared__ float wsm[BKT];
    __shared__ int cur[BKT];
    int b = blockIdx.x, y = blockIdx.y, tid = threadIdx.x;
    int t = batch * 6 + y;
    const uint2* gE = E2 + (size_t)y * EE;
    unsigned int* oE = E1 + (size_t)t * EE;
    const int* off = chunkHist + (size_t)t * NBINS * NCH;
    int e0 = off[b * NCH];
    int e1 = (b == NBINS - 1) ? EE : off[(b + 1) * NCH];
    int seg = e1 - e0;
    for (int i = tid; i < seg; i += 256) es[i] = gE[e0 + i];
    if (tid < BKT) { cnt[tid] = 0; wsm[tid] = 0.0f; }
    __syncthreads();
    for (int i = tid; i < seg; i += 256) {
        int dl = (es[i].x >> 16) & 127;
        atomicAdd(&cnt[dl], 1);
        atomicAdd(&wsm[dl], __uint_as_float(es[i].y));
    }
    __syncthreads();
    int ogv = (tid < BKT) ? cnt[tid] : 0;
    for (int o = 1; o < BKT; o <<= 1) {
        int u = (tid < BKT && tid >= o) ? cnt[tid - o] : 0;
        __syncthreads();
        if (tid < BKT) cnt[tid] += u;
        __syncthreads();
    }
    if (tid < BKT) {
        int exc = cnt[tid] - ogv;
        cur[tid] = exc;
        float dv = rsqrtf(1.0f + wsm[tid]);
        wsm[tid] = dv;   // reuse as dinv-local
        int node = b * BKT + tid;
        if (node <= NN) {
            rowptr[(size_t)t * RP + node] = e0 + exc;
            if (node < NN) dinvG[(size_t)t * NN + node] = dv;
        }
    }
    __syncthreads();
    for (int i = tid; i < seg; i += 256) {
        uint2 p = es[i];
        int dl = (p.x >> 16) & 127;
        int pos = atomicAdd(&cur[dl], 1);
        float wv = __uint_as_float(p.y) * wsm[dl];
        oE[e0 + pos] = (p.x & 0xFFFF) | ((unsigned int)f_to_h16(wv) << 16);
    }
}

// S4b: xs[t][n][f] = (f16)(dinv[t][n] * x[t][n][f])
__global__ void xs_kernel(const float* __restrict__ x, const float* __restrict__ dinvG,
                          _Float16* __restrict__ xs16) {
    int gid = blockIdx.x * 256 + threadIdx.x;   // TT*NN*4 float4 groups (exact: 9375 blocks)
    int tn = gid >> 2;
    float dd = dinvG[tn];
    float4 v = ((const float4*)x)[gid];
    _Float16 h[4] = {(_Float16)(dd * v.x), (_Float16)(dd * v.y),
                     (_Float16)(dd * v.z), (_Float16)(dd * v.w)};
    uint2 o;
    __builtin_memcpy(&o, h, 8);
    ((uint2*)xs16)[gid] = o;
}

// S5: CSR gather: wave per (t,node). 8 edges x 8 feature-pairs per iteration.
// xagg[t][n][f] = sum_e w'_e * xs[s][f] + dinv[n]*xs[n][f]   (all f16 in, f32 acc)
__global__ void gather_csr(const unsigned int* __restrict__ E1, const int* __restrict__ rowptr,
                           const float* __restrict__ dinvG, const _Float16* __restrict__ xs16,
                           _Float16* __restrict__ xagg16) {
    int t = blockIdx.y;
    int n = blockIdx.x * 4 + (threadIdx.x >> 6);
    if (n >= NN) return;
    int lane = threadIdx.x & 63;
    int eo = lane >> 3, fp = lane & 7;
    const unsigned int* gE = E1 + (size_t)t * EE;
    const _Float16* xs = xs16 + (size_t)t * NN * FF;
    int r0 = rowptr[(size_t)t * RP + n], r1 = rowptr[(size_t)t * RP + n + 1];
    float a0 = 0.0f, a1 = 0.0f;
    for (int e = r0 + eo; e < r1; e += 8) {
        unsigned int rec = gE[e];
        float wv = h16_to_f((unsigned short)(rec >> 16));
        unsigned int xp = *(const unsigned int*)(xs + (size_t)(rec & 0xFFFF) * FF + 2 * fp);
        a0 += wv * h16_to_f((unsigned short)(xp & 0xFFFF));
        a1 += wv * h16_to_f((unsigned short)(xp >> 16));
    }
    a0 += __shfl_xor(a0, 8);  a1 += __shfl_xor(a1, 8);
    a0 += __shfl_xor(a0, 16); a1 += __shfl_xor(a1, 16);
    a0 += __shfl_xor(a0, 32); a1 += __shfl_xor(a1, 32);
    if (eo == 0) {
        float dd = dinvG[(size_t)t * NN + n];
        unsigned int xp = *(const unsigned int*)(xs + (size_t)n * FF + 2 * fp);
        float o0 = a0 + dd * h16_to_f((unsigned short)(xp & 0xFFFF));
        float o1 = a1 + dd * h16_to_f((unsigned short)(xp >> 16));
        unsigned int pack = (unsigned int)f_to_h16(o0) | ((unsigned int)f_to_h16(o1) << 16);
        ((unsigned int*)(xagg16 + ((size_t)t * NN + n) * FF))[fp] = pack;
    }
}

// S6 (horizon): 3-feature CSR re-aggregation of predsc (= dinv*pred) over t=11.
__global__ void gather3_csr(const unsigned int* __restrict__ E1, const int* __restrict__ rowptr,
                            const float* __restrict__ dinvG, const float* __restrict__ predsc,
                            _Float16* __restrict__ xaggH16) {
    int n = blockIdx.x * 4 + (threadIdx.x >> 6);
    if (n >= NN) return;
    int lane = threadIdx.x & 63;
    int eo = lane >> 2, f = lane & 3;
    const unsigned int* gE = E1 + (size_t)11 * EE;
    const float* dv = dinvG + (size_t)11 * NN;
    int r0 = rowptr[(size_t)11 * RP + n], r1 = rowptr[(size_t)11 * RP + n + 1];
    float acc = 0.0f;
    for (int e = r0 + eo; e < r1; e += 16) {
        unsigned int rec = gE[e];
        float wv = h16_to_f((unsigned short)(rec >> 16));
        if (f < 3) acc += wv * predsc[(size_t)(rec & 0xFFFF) * 4 + f];
    }
    acc += __shfl_xor(acc, 4);
    acc += __shfl_xor(acc, 8);
    acc += __shfl_xor(acc, 16);
    acc += __shfl_xor(acc, 32);
    if (lane < 3) {
        float res = acc + dv[n] * predsc[(size_t)n * 4 + f];
        xaggH16[(size_t)n * FF + f] = (_Float16)res;
    }
}

// ---------------------------------------------------------------------------
// W: fold Wc into Wl_top -> BcatT[g][n=128][k: h(0..127) | x(128..143) | 0(144..159)]
__global__ void weight_kernel(const float* Wc0, const float* bc0, const float* Wl0, const float* bl0,
                              const float* Wc1, const float* bc1, const float* Wl1, const float* bl1,
                              const float* Wc2, const float* bc2, const float* Wl2, const float* bl2,
                              _Float16* __restrict__ BcatT, float* __restrict__ beff) {
    __shared__ float WcS[FF][HH];
    int g = blockIdx.x;
    int n = threadIdx.x;  // 128
    const float* Wc = g == 0 ? Wc0 : (g == 1 ? Wc1 : Wc2);
    const float* bc = g == 0 ? bc0 : (g == 1 ? bc1 : bc2);
    const float* Wl = g == 0 ? Wl0 : (g == 1 ? Wl1 : Wl2);
    const float* bl = g == 0 ? bl0 : (g == 1 ? bl1 : bl2);
    for (int q = 0; q < FF; q++) WcS[q][n] = Wc[q * HH + n];
    __syncthreads();
    float acc[FF];
#pragma unroll
    for (int i = 0; i < FF; i++) acc[i] = 0.0f;
    float accb = 0.0f;
    for (int k = 0; k < HH; k++) {
        float wl = Wl[k * HH + n];
        accb += bc[k] * wl;
#pragma unroll
        for (int i = 0; i < FF; i++) acc[i] += WcS[i][k] * wl;
    }
    _Float16* row = BcatT + ((size_t)g * HH + n) * BKROW;
    for (int j = 0; j < HH; j++) row[j] = (_Float16)Wl[(size_t)(HH + j) * HH + n];
#pragma unroll
    for (int i = 0; i < FF; i++) row[HH + i] = (_Float16)acc[i];
#pragma unroll
    for (int i = 144; i < 160; i++) row[i] = (_Float16)0.0f;
    beff[g * HH + n] = bl[n] + accb;
}

// ---------------------------------------------------------------------------
// CELLSEQ v2b: fused multi-step GRU cell, TRANSPOSED MFMA.
//  - 512 threads = 8 waves; each wave owns 16 output cols for all 64 rows.
//  - mfma(W_frag, hx_frag, acc): D[gatecol = col0+quad*4+i][node = mrow] -> the
//    epilogue/rescale/hprev paths are vectorized b64 LDS ops (no scalar LDS,
//    no 4-way bank conflicts).
//  - Weights streamed from L2 each phase (BcatT = 120KB, L2-resident): keeps
//    peak regs <=128 so __launch_bounds__(512,4) gives 16 waves/CU.
//  - Separate rescaled buffer Ar -> 3 barriers/step.
//  - single mode writes hio directly from the epilogue (no Hc staging/copy).
__launch_bounds__(512, 4)
__global__ void cellseq_kernel(const _Float16* __restrict__ xaggBase,
                               _Float16* __restrict__ hio,
                               const _Float16* __restrict__ BcatT,
                               const float* __restrict__ beff,
                               const unsigned char* __restrict__ hmAll,
                               const unsigned char* __restrict__ mcAll,
                               int nsteps) {
    __shared__ _Float16 Ah[64 * AH_STR];   // 17408 B : pre-rescale h-part of A
    __shared__ _Float16 Ar[64 * AH_STR];   // 17408 B : rescaled h-part (h * sig(r))
    __shared__ _Float16 Ax[64 * AX_STR];   //  5120 B : x-part (k 128..143) + zero pad
    __shared__ _Float16 Hc[64 * HC_STR];   // 17408 B : committed h
    const int tid = threadIdx.x;           // 0..511
    const int m0 = blockIdx.x * 64;
    const int lane = tid & 63;
    const int w = tid >> 6;                // 0..7
    const int mrow = lane & 15;
    const int quad = lane >> 4;
    const int col0 = w * 16;
    const int cb = col0 + quad * 4;        // this lane's 4 output cols
    const bool rec = (hmAll != nullptr);

    // persistent per-lane biases (own 4 cols)
    const float4 bz4 = *(const float4*)(beff + cb);
    const float4 br4 = *(const float4*)(beff + HH + cb);
    const float4 bh4 = *(const float4*)(beff + 2 * HH + cb);

    // weight fragment base pointers (A-operand rows = gate cols = col0+mrow)
    const _Float16* Wzp = BcatT + (size_t)(col0 + mrow) * BKROW + quad * 8;
    const _Float16* Wrp = Wzp + (size_t)HH * BKROW;
    const _Float16* Whp = Wzp + (size_t)2 * HH * BKROW;

    // zero Ax pad (k 144..159) + init Hc in rec mode
    for (int idx = tid; idx < 128; idx += 512) {
        int row = idx >> 1, q = idx & 1;
        *(uint4*)(Ax + row * AX_STR + 16 + q * 8) = make_uint4(0, 0, 0, 0);
    }
    if (rec) {
        for (int idx = tid; idx < 1024; idx += 512) {
            int row = idx >> 4, q = idx & 15;
            *(uint4*)(Hc + row * HC_STR + q * 8) = make_uint4(0, 0, 0, 0);
        }
    }
    __syncthreads();

    for (int t = 0; t < nsteps; t++) {
        const _Float16* xa = xaggBase + (size_t)t * NN * FF;
        const unsigned char* hm = rec ? (hmAll + (size_t)t * NN) : nullptr;
        const unsigned char* mc = rec ? (mcAll + (size_t)t * NN) : nullptr;

        // ---- build A: Ah = (hm ? Hc : 0) | hio (single mode); Ax = xagg ----
        for (int idx = tid; idx < 1024; idx += 512) {
            int row = idx >> 4, q = idx & 15;
            int g = m0 + row;
            uint4 v = make_uint4(0, 0, 0, 0);
            if (rec) {
                if (g < NN && hm[g]) v = *(const uint4*)(Hc + row * HC_STR + q * 8);
            } else {
                if (g < NN) v = *(const uint4*)(hio + (size_t)g * HH + q * 8);
            }
            *(uint4*)(Ah + row * AH_STR + q * 8) = v;
        }
        for (int idx = tid; idx < 128; idx += 512) {
            int row = idx >> 1, q = idx & 1;
            int g = m0 + row;
            uint4 v = make_uint4(0, 0, 0, 0);
            if (g < NN) v = *(const uint4*)(xa + (size_t)g * FF + q * 8);
            *(uint4*)(Ax + row * AX_STR + q * 8) = v;
        }
        __syncthreads();   // bar1: A complete

        // ---- phase A: z and r MFMAs + rescale -> Ar ----
        half8_t wz[5], wr[5];
#pragma unroll
        for (int ks = 0; ks < 5; ks++) {
            wz[ks] = *(const half8_t*)(Wzp + ks * 32);
            wr[ks] = *(const half8_t*)(Wrp + ks * 32);
        }
        floatx4 zacc[4];
        unsigned int hpw[4][2];   // hprev (own 4 cols per node-tile), packed f16
#pragma unroll
        for (int nt = 0; nt < 4; nt++) {
            const _Float16* hxp = Ah + (nt * 16 + mrow) * AH_STR + quad * 8;
            half8_t hx[5];
#pragma unroll
            for (int ks = 0; ks < 4; ks++) hx[ks] = *(const half8_t*)(hxp + ks * 32);
            hx[4] = *(const half8_t*)(Ax + (nt * 16 + mrow) * AX_STR + quad * 8);
            floatx4 za = {0.0f, 0.0f, 0.0f, 0.0f}, ra = {0.0f, 0.0f, 0.0f, 0.0f};
#pragma unroll
            for (int ks = 0; ks < 5; ks++)
                za = __builtin_amdgcn_mfma_f32_16x16x32_f16(wz[ks], hx[ks], za, 0, 0, 0);
#pragma unroll
            for (int ks = 0; ks < 5; ks++)
                ra = __builtin_amdgcn_mfma_f32_16x16x32_f16(wr[ks], hx[ks], ra, 0, 0, 0);
            zacc[nt] = za;
            // hprev for own (node = nt*16+mrow, cols cb..cb+3): one b64 read
            uint2 hp = *(const uint2*)(Ah + (nt * 16 + mrow) * AH_STR + cb);
            hpw[nt][0] = hp.x; hpw[nt][1] = hp.y;
            float r0 = fsig(ra[0] + br4.x), r1 = fsig(ra[1] + br4.y);
            float r2 = fsig(ra[2] + br4.z), r3 = fsig(ra[3] + br4.w);
            float hp0 = h16_to_f((unsigned short)(hp.x & 0xFFFF));
            float hp1 = h16_to_f((unsigned short)(hp.x >> 16));
            float hp2 = h16_to_f((unsigned short)(hp.y & 0xFFFF));
            float hp3 = h16_to_f((unsigned short)(hp.y >> 16));
            uint2 o;
            o.x = (unsigned int)f_to_h16(hp0 * r0) | ((unsigned int)f_to_h16(hp1 * r1) << 16);
            o.y = (unsigned int)f_to_h16(hp2 * r2) | ((unsigned int)f_to_h16(hp3 * r3) << 16);
            *(uint2*)(Ar + (nt * 16 + mrow) * AH_STR + cb) = o;
        }
        __syncthreads();   // bar2: Ar complete, Ah reads done

        // ---- phase B: h~ MFMAs from Ar|Ax + epilogue ----
        half8_t wh[5];
#pragma unroll
        for (int ks = 0; ks < 5; ks++) wh[ks] = *(const half8_t*)(Whp + ks * 32);
#pragma unroll
        for (int nt = 0; nt < 4; nt++) {
            const _Float16* hxp = Ar + (nt * 16 + mrow) * AH_STR + quad * 8;
            half8_t hx[5];
#pragma unroll
            for (int ks = 0; ks < 4; ks++) hx[ks] = *(const half8_t*)(hxp + ks * 32);
            hx[4] = *(const half8_t*)(Ax + (nt * 16 + mrow) * AX_STR + quad * 8);
            floatx4 ha = {0.0f, 0.0f, 0.0f, 0.0f};
#pragma unroll
            for (int ks = 0; ks < 5; ks++)
                ha = __builtin_amdgcn_mfma_f32_16x16x32_f16(wh[ks], hx[ks], ha, 0, 0, 0);
            int g = m0 + nt * 16 + mrow;
            if (g < NN) {
                float z0 = fsig(zacc[nt][0] + bz4.x), z1 = fsig(zacc[nt][1] + bz4.y);
                float z2 = fsig(zacc[nt][2] + bz4.z), z3 = fsig(zacc[nt][3] + bz4.w);
                float t0 = ftanh(ha[0] + bh4.x), t1 = ftanh(ha[1] + bh4.y);
                float t2 = ftanh(ha[2] + bh4.z), t3 = ftanh(ha[3] + bh4.w);
                float hp0 = h16_to_f((unsigned short)(hpw[nt][0] & 0xFFFF));
                float hp1 = h16_to_f((unsigned short)(hpw[nt][0] >> 16));
                float hp2 = h16_to_f((unsigned short)(hpw[nt][1] & 0xFFFF));
                float hp3 = h16_to_f((unsigned short)(hpw[nt][1] >> 16));
                float n0 = z0 * hp0 + (1.0f - z0) * t0;
                float n1 = z1 * hp1 + (1.0f - z1) * t1;
                float n2 = z2 * hp2 + (1.0f - z2) * t2;
                float n3 = z3 * hp3 + (1.0f - z3) * t3;
                uint2 o;
                o.x = (unsigned int)f_to_h16(n0) | ((unsigned int)f_to_h16(n1) << 16);
                o.y = (unsigned int)f_to_h16(n2) | ((unsigned int)f_to_h16(n3) << 16);
                if (rec) {
                    if (mc[g]) *(uint2*)(Hc + (nt * 16 + mrow) * HC_STR + cb) = o;
                } else {
                    // single-step: write result directly to global (no staging)
                    *(uint2*)(hio + (size_t)g * HH + cb) = o;
                }
            }
        }
        __syncthreads();   // bar3: Hc committed / Ar+Ax readers done
    }

    // ---- final (rec only): hio = mc[last] ? Hc : 0 ----
    if (rec) {
        const unsigned char* mcL = mcAll + (size_t)(nsteps - 1) * NN;
        for (int idx = tid; idx < 1024; idx += 512) {
            int row = idx >> 4, q = idx & 15;
            int g = m0 + row;
            if (g < NN) {
                uint4 v = make_uint4(0, 0, 0, 0);
                if (mcL[g]) v = *(const uint4*)(Hc + row * HC_STR + q * 8);
                *(uint4*)(hio + (size_t)g * HH + q * 8) = v;
            }
        }
    }
}

// C4: out[n][o] = h . head_W[:,o] + head_b[o]; also predsc[n][o] = dinv11[n]*out
__global__ void head_kernel(const _Float16* __restrict__ hp, const float* __restrict__ headW,
                            const float* __restrict__ headb, const float* __restrict__ dinv11,
                            float* __restrict__ out, float* __restrict__ predsc) {
    int node = (blockIdx.x * 256 + threadIdx.x) >> 6;
    int lane = threadIdx.x & 63;
    if (node >= NN) return;
    const _Float16* h = hp + (size_t)node * HH;
    float h0 = (float)h[lane], h1 = (float)h[64 + lane];
    float s0 = h0 * headW[lane * 3 + 0] + h1 * headW[(64 + lane) * 3 + 0];
    float s1 = h0 * headW[lane * 3 + 1] + h1 * headW[(64 + lane) * 3 + 1];
    float s2 = h0 * headW[lane * 3 + 2] + h1 * headW[(64 + lane) * 3 + 2];
#pragma unroll
    for (int off = 32; off > 0; off >>= 1) {
        s0 += __shfl_down(s0, off);
        s1 += __shfl_down(s1, off);
        s2 += __shfl_down(s2, off);
    }
    if (lane == 0) {
        float o0 = s0 + headb[0], o1 = s1 + headb[1], o2 = s2 + headb[2];
        out[(size_t)node * 3 + 0] = o0;
        out[(size_t)node * 3 + 1] = o1;
        out[(size_t)node * 3 + 2] = o2;
        float dd = dinv11[node];
        predsc[(size_t)node * 4 + 0] = dd * o0;
        predsc[(size_t)node * 4 + 1] = dd * o1;
        predsc[(size_t)node * 4 + 2] = dd * o2;
    }
}

extern "C" void kernel_launch(void* const* d_in, const int* in_sizes, int n_in,
                              void* d_out, int out_size, void* d_ws, size_t ws_size,
                              hipStream_t stream) {
    const float* x = (const float*)d_in[0];
    const int* ei = (const int*)d_in[1];
    const float* ea = (const float*)d_in[2];
    const void* mask = d_in[3];
    const float* Wc[3] = {(const float*)d_in[4], (const float*)d_in[8], (const float*)d_in[12]};
    const float* bc[3] = {(const float*)d_in[5], (const float*)d_in[9], (const float*)d_in[13]};
    const float* Wl[3] = {(const float*)d_in[6], (const float*)d_in[10], (const float*)d_in[14]};
    const float* bl[3] = {(const float*)d_in[7], (const float*)d_in[11], (const float*)d_in[15]};
    const float* headW = (const float*)d_in[16];
    const float* headb = (const float*)d_in[17];
    float* out = (float*)d_out;

    char* w = (char*)d_ws;
    auto alloc = [&](size_t bytes) {
        char* p = w;
        w += (bytes + 255) & ~(size_t)255;
        return p;
    };
    float* dinv = (float*)alloc((size_t)TT * NN * 4);
    _Float16* xagg16 = (_Float16*)alloc((size_t)TT * NN * FF * 2);
    _Float16* xaggH16 = (_Float16*)alloc((size_t)NN * FF * 2);
    _Float16* xs16 = (_Float16*)alloc((size_t)TT * NN * FF * 2);
    int* chunkHist = (int*)alloc((size_t)TT * NBINS * NCH * 4);
    int* rowptr = (int*)alloc((size_t)TT * RP * 4);
    unsigned int* E1 = (unsigned int*)alloc((size_t)TT * EE * 4);  // compact CSR records
    uint2* E2 = (uint2*)alloc((size_t)6 * EE * 8);                 // staging, 6 slots (2 batches)
    _Float16* BcatT = (_Float16*)alloc((size_t)3 * HH * BKROW * 2);
    float* beff = (float*)alloc(3 * HH * 4);
    float* predsc = (float*)alloc((size_t)NN * 4 * 4);
    unsigned char* hm = (unsigned char*)alloc((size_t)TT * NN);
    unsigned char* mc = (unsigned char*)alloc((size_t)TT * NN);
    int* flag = (int*)alloc(64);

    // f16 horizon hidden state aliases the E2 staging area (dead after sortbin).
    _Float16* hph = (_Float16*)E2;   // 12.8 MB

    detect_mask<<<1, 256, 0, stream>>>((const unsigned char*)mask, flag);
    build_masks<<<(NN + 255) / 256, 256, 0, stream>>>(mask, flag, hm, mc);

    hist_kernel<<<dim3(NCH, TT), 256, 0, stream>>>(ei, chunkHist);
    scan_kernel<<<TT, 1024, 0, stream>>>(chunkHist);
    for (int b = 0; b < 2; b++) {
        scatter_kernel<<<dim3(NCH, 6), 256, 0, stream>>>(ei, ea, chunkHist, E2, b);
        sortbin_kernel<<<dim3(NBINS, 6), 256, 0, stream>>>(E2, chunkHist, E1, rowptr, dinv, b);
    }
    xs_kernel<<<TT * NN * 4 / 256, 256, 0, stream>>>(x, dinv, xs16);
    gather_csr<<<dim3((NN + 3) / 4, TT), 256, 0, stream>>>(E1, rowptr, dinv, xs16, xagg16);

    weight_kernel<<<3, 128, 0, stream>>>(Wc[0], bc[0], Wl[0], bl[0],
                                         Wc[1], bc[1], Wl[1], bl[1],
                                         Wc[2], bc[2], Wl[2], bl[2], BcatT, beff);

    // fused recurrent chain t=0..11: h resident in LDS, writes hph = mc11 ? h : 0
    cellseq_kernel<<<CGB, 512, 0, stream>>>(xagg16, hph, BcatT, beff, hm, mc, TT);

    hipMemcpyAsync(xaggH16, xagg16 + (size_t)11 * NN * FF, (size_t)NN * FF * 2,
                   hipMemcpyDeviceToDevice, stream);

    for (int k = 0; k < 6; k++) {
        const _Float16* xa = (k == 0) ? (xagg16 + (size_t)11 * NN * FF) : xaggH16;
        cellseq_kernel<<<CGB, 512, 0, stream>>>(xa, hph, BcatT, beff, nullptr, nullptr, 1);
        head_kernel<<<NN * 64 / 256, 256, 0, stream>>>(hph, headW, headb, dinv + (size_t)11 * NN,
                                                       out + (size_t)k * NN * 3, predsc);
        if (k < 5) {
            gather3_csr<<<(NN + 3) / 4, 256, 0, stream>>>(E1, rowptr, dinv, predsc, xaggH16);
        }
    }
}

// Round 5
// 1953.536 us; speedup vs baseline: 1.0980x; 1.0980x over previous
//
#include <hip/hip_runtime.h>
#include <math.h>

#define NN 50000
#define TT 12
#define EE 1600000
#define FF 16
#define HH 128
#define CHK 4096     // edges per chunk (level-1 histogram / scatter staging)
#define NCH 391      // ceil(EE/CHK)
#define BKT 128      // nodes per bin
#define NBINS 391    // ceil(NN/BKT) -> covers 50048
#define CAP 6144     // max edges per bin segment (mean 4096, sigma 64)
#define RP 50016     // rowptr stride per t (>= NN+1)
#define CGB 782      // ceil(NN/64) cell blocks
#define AH_STR 136   // h-part A LDS stride (halves): 272B rows
#define AX_STR 40    // x-part A LDS stride (halves)
#define HC_STR 136   // committed-h LDS stride (halves)
#define BKROW 160    // BcatT row stride in halves: [h 0..127 | x 128..143 | zero 144..159]

typedef _Float16 half8_t __attribute__((ext_vector_type(8)));
typedef float floatx4 __attribute__((ext_vector_type(4)));

__device__ __forceinline__ float h16_to_f(unsigned short u) {
    _Float16 h; __builtin_memcpy(&h, &u, 2); return (float)h;
}
__device__ __forceinline__ unsigned short f_to_h16(float f) {
    _Float16 h = (_Float16)f; unsigned short u; __builtin_memcpy(&u, &h, 2); return u;
}
__device__ __forceinline__ float fsig(float x) {
    return 1.0f / (1.0f + exp2f(-1.44269504f * x));
}
__device__ __forceinline__ float ftanh(float x) {
    return 2.0f / (1.0f + exp2f(-2.88539009f * x)) - 1.0f;
}

// ---------------------------------------------------------------------------
// P0: detect mask dtype from byte pattern (uint8 / int32 / float32).
__global__ void detect_mask(const unsigned char* __restrict__ m, int* __restrict__ flag) {
    __shared__ int cnt[2];
    if (threadIdx.x < 2) cnt[threadIdx.x] = 0;
    __syncthreads();
    int a = 0, b = 0;
    for (int base = 0; base < 4096; base += 256) {
        int idx = base + threadIdx.x;
        unsigned char v = m[idx];
        int r = idx & 3;
        if (v) { if (r == 0) a++; else if (r == 1) b++; }
    }
    atomicAdd(&cnt[0], a);
    atomicAdd(&cnt[1], b);
    __syncthreads();
    if (threadIdx.x == 0) flag[0] = cnt[1] > 0 ? 0 : (cnt[0] > 0 ? 1 : 2);
}

// P1: hm[t][n] = mask & seen-before, mc[t][n] = mask
__global__ void build_masks(const void* __restrict__ mask, const int* __restrict__ flag,
                            unsigned char* __restrict__ hm, unsigned char* __restrict__ mc) {
    int n = blockIdx.x * 256 + threadIdx.x;
    if (n >= NN) return;
    int mode = flag[0];
    bool seen = false;
    for (int t = 0; t < TT; t++) {
        int idx = t * NN + n;
        bool m;
        if (mode == 0)      m = ((const unsigned char*)mask)[idx] != 0;
        else if (mode == 1) m = ((const int*)mask)[idx] != 0;
        else                m = ((const float*)mask)[idx] != 0.0f;
        hm[idx] = (m && seen) ? 1 : 0;
        mc[idx] = m ? 1 : 0;
        seen = seen || m;
    }
}

// ---------------------------------------------------------------------------
// S1: per-chunk histogram of dst bins (bin = dst>>7). layout [t][bin][chunk]
__global__ void hist_kernel(const int* __restrict__ ei, int* __restrict__ chunkHist) {
    __shared__ int h[NBINS + 1];
    int c = blockIdx.x, t = blockIdx.y, tid = threadIdx.x;
    for (int i = tid; i < NBINS; i += 256) h[i] = 0;
    __syncthreads();
    const int* dstp = ei + (size_t)(2 * t + 1) * EE;
    int e0 = c * CHK;
    for (int i = tid; i < CHK; i += 256) {
        int e = e0 + i;
        if (e < EE) atomicAdd(&h[dstp[e] >> 7], 1);
    }
    __syncthreads();
    for (int i = tid; i < NBINS; i += 256)
        chunkHist[((size_t)t * NBINS + i) * NCH + c] = h[i];
}

// S2: in-place exclusive scan of each t's [NBINS*NCH] array
__global__ void scan_kernel(int* __restrict__ buf) {
    __shared__ int ps[1024];
    const int L = NBINS * NCH;   // 152881
    const int PER = 150;         // 1024*150 >= L
    int t = blockIdx.x, tid = threadIdx.x;
    int* a = buf + (size_t)t * L;
    int i0 = tid * PER, i1 = min(i0 + PER, L);
    int s = 0;
    for (int i = i0; i < i1; i++) s += a[i];
    ps[tid] = s;
    __syncthreads();
    for (int off = 1; off < 1024; off <<= 1) {
        int v = (tid >= off) ? ps[tid - off] : 0;
        __syncthreads();
        ps[tid] += v;
        __syncthreads();
    }
    int base = (tid == 0) ? 0 : ps[tid - 1];
    for (int i = i0; i < i1; i++) { int v = a[i]; a[i] = base; base += v; }
}

// S3: LDS-staged scatter into bin-sorted order (batch of 6 t's).
// Record: uint2{src|dst<<16, w_f32}. Coalesced segment write-out.
__launch_bounds__(256)
__global__ void scatter_kernel(const int* __restrict__ ei, const float* __restrict__ ea,
                               const int* __restrict__ chunkOff, uint2* __restrict__ E2,
                               int batch) {
    __shared__ uint2 sorted[CHK];          // 32 KB
    __shared__ int cnt[NBINS];
    __shared__ int sA[NBINS], sB[NBINS];
    __shared__ int start[NBINS], gbase[NBINS];
    int c = blockIdx.x, y = blockIdx.y, tid = threadIdx.x;
    int t = batch * 6 + y;
    for (int i = tid; i < NBINS; i += 256) {
        cnt[i] = 0;
        gbase[i] = chunkOff[((size_t)t * NBINS + i) * NCH + c];
    }
    __syncthreads();
    const int* srcp = ei + (size_t)(2 * t) * EE;
    const int* dstp = ei + (size_t)(2 * t + 1) * EE;
    const float* wp = ea + (size_t)t * EE;
    int e0 = c * CHK;
    int m = min(CHK, EE - e0);
    uint2 rec[16];
    int rank[16];
#pragma unroll
    for (int k = 0; k < 16; k++) {
        int i = k * 256 + tid;
        rank[k] = -1;
        if (i < m) {
            int e = e0 + i;
            unsigned int s = (unsigned int)srcp[e];
            unsigned int d = (unsigned int)dstp[e];
            float wv = wp[e];
            rec[k].x = s | (d << 16);
            rec[k].y = __float_as_uint(wv);
            rank[k] = atomicAdd(&cnt[d >> 7], 1);
        }
    }
    __syncthreads();
    for (int i = tid; i < NBINS; i += 256) sA[i] = cnt[i];
    __syncthreads();
    int pp = 0;
    for (int off = 1; off < NBINS; off <<= 1) {
        if (pp == 0) {
            for (int i = tid; i < NBINS; i += 256)
                sB[i] = (i >= off) ? sA[i] + sA[i - off] : sA[i];
        } else {
            for (int i = tid; i < NBINS; i += 256)
                sA[i] = (i >= off) ? sB[i] + sB[i - off] : sB[i];
        }
        pp ^= 1;
        __syncthreads();
    }
    const int* inc = pp ? sB : sA;
    for (int i = tid; i < NBINS; i += 256) start[i] = inc[i] - cnt[i];
    __syncthreads();
#pragma unroll
    for (int k = 0; k < 16; k++) {
        if (rank[k] >= 0) {
            int b = rec[k].x >> 23;
            sorted[start[b] + rank[k]] = rec[k];
        }
    }
    __syncthreads();
    uint2* outp = E2 + (size_t)y * EE;
    for (int i = tid; i < m; i += 256) {
        uint2 r = sorted[i];
        int b = r.x >> 23;
        outp[gbase[b] + (i - start[b])] = r;
    }
}

// S4: per-bin counting sort -> compact CSR records (src u16 | w'=w*dinv[d] f16)
// + rowptr + dinv. Reads uint2 staging E2, writes 4B records to E1.
__launch_bounds__(256)
__global__ void sortbin_kernel(const uint2* __restrict__ E2, const int* __restrict__ chunkHist,
                               unsigned int* __restrict__ E1, int* __restrict__ rowptr,
                               float* __restrict__ dinvG, int batch) {
    __shared__ uint2 es[CAP];   // 48 KB
    __shared__ int cnt[BKT];
    __shared__ float wsm[BKT];
    __shared__ int cur[BKT];
    int b = blockIdx.x, y = blockIdx.y, tid = threadIdx.x;
    int t = batch * 6 + y;
    const uint2* gE = E2 + (size_t)y * EE;
    unsigned int* oE = E1 + (size_t)t * EE;
    const int* off = chunkHist + (size_t)t * NBINS * NCH;
    int e0 = off[b * NCH];
    int e1 = (b == NBINS - 1) ? EE : off[(b + 1) * NCH];
    int seg = e1 - e0;
    for (int i = tid; i < seg; i += 256) es[i] = gE[e0 + i];
    if (tid < BKT) { cnt[tid] = 0; wsm[tid] = 0.0f; }
    __syncthreads();
    for (int i = tid; i < seg; i += 256) {
        int dl = (es[i].x >> 16) & 127;
        atomicAdd(&cnt[dl], 1);
        atomicAdd(&wsm[dl], __uint_as_float(es[i].y));
    }
    __syncthreads();
    int ogv = (tid < BKT) ? cnt[tid] : 0;
    for (int o = 1; o < BKT; o <<= 1) {
        int u = (tid < BKT && tid >= o) ? cnt[tid - o] : 0;
        __syncthreads();
        if (tid < BKT) cnt[tid] += u;
        __syncthreads();
    }
    if (tid < BKT) {
        int exc = cnt[tid] - ogv;
        cur[tid] = exc;
        float dv = rsqrtf(1.0f + wsm[tid]);
        wsm[tid] = dv;   // reuse as dinv-local
        int node = b * BKT + tid;
        if (node <= NN) {
            rowptr[(size_t)t * RP + node] = e0 + exc;
            if (node < NN) dinvG[(size_t)t * NN + node] = dv;
        }
    }
    __syncthreads();
    for (int i = tid; i < seg; i += 256) {
        uint2 p = es[i];
        int dl = (p.x >> 16) & 127;
        int pos = atomicAdd(&cur[dl], 1);
        float wv = __uint_as_float(p.y) * wsm[dl];
        oE[e0 + pos] = (p.x & 0xFFFF) | ((unsigned int)f_to_h16(wv) << 16);
    }
}

// S4b: xs[t][n][f] = (f16)(dinv[t][n] * x[t][n][f])
__global__ void xs_kernel(const float* __restrict__ x, const float* __restrict__ dinvG,
                          _Float16* __restrict__ xs16) {
    int gid = blockIdx.x * 256 + threadIdx.x;   // TT*NN*4 float4 groups (exact: 9375 blocks)
    int tn = gid >> 2;
    float dd = dinvG[tn];
    float4 v = ((const float4*)x)[gid];
    _Float16 h[4] = {(_Float16)(dd * v.x), (_Float16)(dd * v.y),
                     (_Float16)(dd * v.z), (_Float16)(dd * v.w)};
    uint2 o;
    __builtin_memcpy(&o, h, 8);
    ((uint2*)xs16)[gid] = o;
}

// S5: CSR gather: wave per (t,node). 8 edges x 8 feature-pairs per iteration.
// xagg[t][n][f] = sum_e w'_e * xs[s][f] + dinv[n]*xs[n][f]   (all f16 in, f32 acc)
__global__ void gather_csr(const unsigned int* __restrict__ E1, const int* __restrict__ rowptr,
                           const float* __restrict__ dinvG, const _Float16* __restrict__ xs16,
                           _Float16* __restrict__ xagg16) {
    int t = blockIdx.y;
    int n = blockIdx.x * 4 + (threadIdx.x >> 6);
    if (n >= NN) return;
    int lane = threadIdx.x & 63;
    int eo = lane >> 3, fp = lane & 7;
    const unsigned int* gE = E1 + (size_t)t * EE;
    const _Float16* xs = xs16 + (size_t)t * NN * FF;
    int r0 = rowptr[(size_t)t * RP + n], r1 = rowptr[(size_t)t * RP + n + 1];
    float a0 = 0.0f, a1 = 0.0f;
    for (int e = r0 + eo; e < r1; e += 8) {
        unsigned int rec = gE[e];
        float wv = h16_to_f((unsigned short)(rec >> 16));
        unsigned int xp = *(const unsigned int*)(xs + (size_t)(rec & 0xFFFF) * FF + 2 * fp);
        a0 += wv * h16_to_f((unsigned short)(xp & 0xFFFF));
        a1 += wv * h16_to_f((unsigned short)(xp >> 16));
    }
    a0 += __shfl_xor(a0, 8);  a1 += __shfl_xor(a1, 8);
    a0 += __shfl_xor(a0, 16); a1 += __shfl_xor(a1, 16);
    a0 += __shfl_xor(a0, 32); a1 += __shfl_xor(a1, 32);
    if (eo == 0) {
        float dd = dinvG[(size_t)t * NN + n];
        unsigned int xp = *(const unsigned int*)(xs + (size_t)n * FF + 2 * fp);
        float o0 = a0 + dd * h16_to_f((unsigned short)(xp & 0xFFFF));
        float o1 = a1 + dd * h16_to_f((unsigned short)(xp >> 16));
        unsigned int pack = (unsigned int)f_to_h16(o0) | ((unsigned int)f_to_h16(o1) << 16);
        ((unsigned int*)(xagg16 + ((size_t)t * NN + n) * FF))[fp] = pack;
    }
}

// S6 (horizon): 3-feature CSR re-aggregation of predsc (= dinv*pred) over t=11.
__global__ void gather3_csr(const unsigned int* __restrict__ E1, const int* __restrict__ rowptr,
                            const float* __restrict__ dinvG, const float* __restrict__ predsc,
                            _Float16* __restrict__ xaggH16) {
    int n = blockIdx.x * 4 + (threadIdx.x >> 6);
    if (n >= NN) return;
    int lane = threadIdx.x & 63;
    int eo = lane >> 2, f = lane & 3;
    const unsigned int* gE = E1 + (size_t)11 * EE;
    const float* dv = dinvG + (size_t)11 * NN;
    int r0 = rowptr[(size_t)11 * RP + n], r1 = rowptr[(size_t)11 * RP + n + 1];
    float acc = 0.0f;
    for (int e = r0 + eo; e < r1; e += 16) {
        unsigned int rec = gE[e];
        float wv = h16_to_f((unsigned short)(rec >> 16));
        if (f < 3) acc += wv * predsc[(size_t)(rec & 0xFFFF) * 4 + f];
    }
    acc += __shfl_xor(acc, 4);
    acc += __shfl_xor(acc, 8);
    acc += __shfl_xor(acc, 16);
    acc += __shfl_xor(acc, 32);
    if (lane < 3) {
        float res = acc + dv[n] * predsc[(size_t)n * 4 + f];
        xaggH16[(size_t)n * FF + f] = (_Float16)res;
    }
}

// ---------------------------------------------------------------------------
// W: fold Wc into Wl_top -> BcatT[g][n=128][k: h(0..127) | x(128..143) | 0(144..159)]
__global__ void weight_kernel(const float* Wc0, const float* bc0, const float* Wl0, const float* bl0,
                              const float* Wc1, const float* bc1, const float* Wl1, const float* bl1,
                              const float* Wc2, const float* bc2, const float* Wl2, const float* bl2,
                              _Float16* __restrict__ BcatT, float* __restrict__ beff) {
    __shared__ float WcS[FF][HH];
    int g = blockIdx.x;
    int n = threadIdx.x;  // 128
    const float* Wc = g == 0 ? Wc0 : (g == 1 ? Wc1 : Wc2);
    const float* bc = g == 0 ? bc0 : (g == 1 ? bc1 : bc2);
    const float* Wl = g == 0 ? Wl0 : (g == 1 ? Wl1 : Wl2);
    const float* bl = g == 0 ? bl0 : (g == 1 ? bl1 : bl2);
    for (int q = 0; q < FF; q++) WcS[q][n] = Wc[q * HH + n];
    __syncthreads();
    float acc[FF];
#pragma unroll
    for (int i = 0; i < FF; i++) acc[i] = 0.0f;
    float accb = 0.0f;
    for (int k = 0; k < HH; k++) {
        float wl = Wl[k * HH + n];
        accb += bc[k] * wl;
#pragma unroll
        for (int i = 0; i < FF; i++) acc[i] += WcS[i][k] * wl;
    }
    _Float16* row = BcatT + ((size_t)g * HH + n) * BKROW;
    for (int j = 0; j < HH; j++) row[j] = (_Float16)Wl[(size_t)(HH + j) * HH + n];
#pragma unroll
    for (int i = 0; i < FF; i++) row[HH + i] = (_Float16)acc[i];
#pragma unroll
    for (int i = 144; i < 160; i++) row[i] = (_Float16)0.0f;
    beff[g * HH + n] = bl[n] + accb;
}

// ---------------------------------------------------------------------------
// CELLSEQ v3: fused multi-step GRU cell, transposed MFMA, ALL WEIGHTS IN REGS.
//  - 512 threads = 8 waves; each wave owns 16 output cols for all 64 rows.
//  - mfma(W_frag, hx_frag, acc): D[gatecol = col0+quad*4+i][node = mrow] ->
//    vectorized b64 epilogue/rescale paths.
//  - wz/wr/wh (5 frags each = 60 VGPRs) hoisted OUT of the t-loop: zero
//    per-step weight traffic, no reload latency.
//  - __launch_bounds__(512, 2): 256-reg cap -> NO SPILLS (v2b at (512,4)
//    allocated 64 VGPRs and spilled ~24 regs/step: 457MB FETCH was scratch).
__launch_bounds__(512, 2)
__global__ void cellseq_kernel(const _Float16* __restrict__ xaggBase,
                               _Float16* __restrict__ hio,
                               const _Float16* __restrict__ BcatT,
                               const float* __restrict__ beff,
                               const unsigned char* __restrict__ hmAll,
                               const unsigned char* __restrict__ mcAll,
                               int nsteps) {
    __shared__ _Float16 Ah[64 * AH_STR];   // 17408 B : pre-rescale h-part of A
    __shared__ _Float16 Ar[64 * AH_STR];   // 17408 B : rescaled h-part (h * sig(r))
    __shared__ _Float16 Ax[64 * AX_STR];   //  5120 B : x-part (k 128..143) + zero pad
    __shared__ _Float16 Hc[64 * HC_STR];   // 17408 B : committed h
    const int tid = threadIdx.x;           // 0..511
    const int m0 = blockIdx.x * 64;
    const int lane = tid & 63;
    const int w = tid >> 6;                // 0..7
    const int mrow = lane & 15;
    const int quad = lane >> 4;
    const int col0 = w * 16;
    const int cb = col0 + quad * 4;        // this lane's 4 output cols
    const bool rec = (hmAll != nullptr);

    // persistent per-lane biases (own 4 cols)
    const float4 bz4 = *(const float4*)(beff + cb);
    const float4 br4 = *(const float4*)(beff + HH + cb);
    const float4 bh4 = *(const float4*)(beff + 2 * HH + cb);

    // persistent weight fragments for ALL gates (A-operand rows = col0+mrow)
    const _Float16* Wzp = BcatT + (size_t)(col0 + mrow) * BKROW + quad * 8;
    half8_t wz[5], wr[5], wh[5];
#pragma unroll
    for (int ks = 0; ks < 5; ks++) {
        wz[ks] = *(const half8_t*)(Wzp + ks * 32);
        wr[ks] = *(const half8_t*)(Wzp + (size_t)HH * BKROW + ks * 32);
        wh[ks] = *(const half8_t*)(Wzp + (size_t)2 * HH * BKROW + ks * 32);
    }

    // zero Ax pad (k 144..159) + init Hc in rec mode
    for (int idx = tid; idx < 128; idx += 512) {
        int row = idx >> 1, q = idx & 1;
        *(uint4*)(Ax + row * AX_STR + 16 + q * 8) = make_uint4(0, 0, 0, 0);
    }
    if (rec) {
        for (int idx = tid; idx < 1024; idx += 512) {
            int row = idx >> 4, q = idx & 15;
            *(uint4*)(Hc + row * HC_STR + q * 8) = make_uint4(0, 0, 0, 0);
        }
    }
    __syncthreads();

    for (int t = 0; t < nsteps; t++) {
        const _Float16* xa = xaggBase + (size_t)t * NN * FF;
        const unsigned char* hm = rec ? (hmAll + (size_t)t * NN) : nullptr;
        const unsigned char* mc = rec ? (mcAll + (size_t)t * NN) : nullptr;

        // ---- build A: Ah = (hm ? Hc : 0) | hio (single mode); Ax = xagg ----
        for (int idx = tid; idx < 1024; idx += 512) {
            int row = idx >> 4, q = idx & 15;
            int g = m0 + row;
            uint4 v = make_uint4(0, 0, 0, 0);
            if (rec) {
                if (g < NN && hm[g]) v = *(const uint4*)(Hc + row * HC_STR + q * 8);
            } else {
                if (g < NN) v = *(const uint4*)(hio + (size_t)g * HH + q * 8);
            }
            *(uint4*)(Ah + row * AH_STR + q * 8) = v;
        }
        for (int idx = tid; idx < 128; idx += 512) {
            int row = idx >> 1, q = idx & 1;
            int g = m0 + row;
            uint4 v = make_uint4(0, 0, 0, 0);
            if (g < NN) v = *(const uint4*)(xa + (size_t)g * FF + q * 8);
            *(uint4*)(Ax + row * AX_STR + q * 8) = v;
        }
        __syncthreads();   // bar1: A complete

        // ---- phase A: z and r MFMAs + rescale -> Ar ----
        floatx4 zacc[4];
        unsigned int hpw[4][2];   // hprev (own 4 cols per node-tile), packed f16
#pragma unroll
        for (int nt = 0; nt < 4; nt++) {
            const _Float16* hxp = Ah + (nt * 16 + mrow) * AH_STR + quad * 8;
            half8_t hx[5];
#pragma unroll
            for (int ks = 0; ks < 4; ks++) hx[ks] = *(const half8_t*)(hxp + ks * 32);
            hx[4] = *(const half8_t*)(Ax + (nt * 16 + mrow) * AX_STR + quad * 8);
            floatx4 za = {0.0f, 0.0f, 0.0f, 0.0f}, ra = {0.0f, 0.0f, 0.0f, 0.0f};
#pragma unroll
            for (int ks = 0; ks < 5; ks++)
                za = __builtin_amdgcn_mfma_f32_16x16x32_f16(wz[ks], hx[ks], za, 0, 0, 0);
#pragma unroll
            for (int ks = 0; ks < 5; ks++)
                ra = __builtin_amdgcn_mfma_f32_16x16x32_f16(wr[ks], hx[ks], ra, 0, 0, 0);
            zacc[nt] = za;
            // hprev for own (node = nt*16+mrow, cols cb..cb+3): one b64 read
            uint2 hp = *(const uint2*)(Ah + (nt * 16 + mrow) * AH_STR + cb);
            hpw[nt][0] = hp.x; hpw[nt][1] = hp.y;
            float r0 = fsig(ra[0] + br4.x), r1 = fsig(ra[1] + br4.y);
            float r2 = fsig(ra[2] + br4.z), r3 = fsig(ra[3] + br4.w);
            float hp0 = h16_to_f((unsigned short)(hp.x & 0xFFFF));
            float hp1 = h16_to_f((unsigned short)(hp.x >> 16));
            float hp2 = h16_to_f((unsigned short)(hp.y & 0xFFFF));
            float hp3 = h16_to_f((unsigned short)(hp.y >> 16));
            uint2 o;
            o.x = (unsigned int)f_to_h16(hp0 * r0) | ((unsigned int)f_to_h16(hp1 * r1) << 16);
            o.y = (unsigned int)f_to_h16(hp2 * r2) | ((unsigned int)f_to_h16(hp3 * r3) << 16);
            *(uint2*)(Ar + (nt * 16 + mrow) * AH_STR + cb) = o;
        }
        __syncthreads();   // bar2: Ar complete, Ah reads done

        // ---- phase B: h~ MFMAs from Ar|Ax + epilogue ----
#pragma unroll
        for (int nt = 0; nt < 4; nt++) {
            const _Float16* hxp = Ar + (nt * 16 + mrow) * AH_STR + quad * 8;
            half8_t hx[5];
#pragma unroll
            for (int ks = 0; ks < 4; ks++) hx[ks] = *(const half8_t*)(hxp + ks * 32);
            hx[4] = *(const half8_t*)(Ax + (nt * 16 + mrow) * AX_STR + quad * 8);
            floatx4 ha = {0.0f, 0.0f, 0.0f, 0.0f};
#pragma unroll
            for (int ks = 0; ks < 5; ks++)
                ha = __builtin_amdgcn_mfma_f32_16x16x32_f16(wh[ks], hx[ks], ha, 0, 0, 0);
            int g = m0 + nt * 16 + mrow;
            if (g < NN) {
                float z0 = fsig(zacc[nt][0] + bz4.x), z1 = fsig(zacc[nt][1] + bz4.y);
                float z2 = fsig(zacc[nt][2] + bz4.z), z3 = fsig(zacc[nt][3] + bz4.w);
                float t0 = ftanh(ha[0] + bh4.x), t1 = ftanh(ha[1] + bh4.y);
                float t2 = ftanh(ha[2] + bh4.z), t3 = ftanh(ha[3] + bh4.w);
                float hp0 = h16_to_f((unsigned short)(hpw[nt][0] & 0xFFFF));
                float hp1 = h16_to_f((unsigned short)(hpw[nt][0] >> 16));
                float hp2 = h16_to_f((unsigned short)(hpw[nt][1] & 0xFFFF));
                float hp3 = h16_to_f((unsigned short)(hpw[nt][1] >> 16));
                float n0 = z0 * hp0 + (1.0f - z0) * t0;
                float n1 = z1 * hp1 + (1.0f - z1) * t1;
                float n2 = z2 * hp2 + (1.0f - z2) * t2;
                float n3 = z3 * hp3 + (1.0f - z3) * t3;
                uint2 o;
                o.x = (unsigned int)f_to_h16(n0) | ((unsigned int)f_to_h16(n1) << 16);
                o.y = (unsigned int)f_to_h16(n2) | ((unsigned int)f_to_h16(n3) << 16);
                if (rec) {
                    if (mc[g]) *(uint2*)(Hc + (nt * 16 + mrow) * HC_STR + cb) = o;
                } else {
                    // single-step: write result directly to global (no staging)
                    *(uint2*)(hio + (size_t)g * HH + cb) = o;
                }
            }
        }
        __syncthreads();   // bar3: Hc committed / Ar+Ax readers done
    }

    // ---- final (rec only): hio = mc[last] ? Hc : 0 ----
    if (rec) {
        const unsigned char* mcL = mcAll + (size_t)(nsteps - 1) * NN;
        for (int idx = tid; idx < 1024; idx += 512) {
            int row = idx >> 4, q = idx & 15;
            int g = m0 + row;
            if (g < NN) {
                uint4 v = make_uint4(0, 0, 0, 0);
                if (mcL[g]) v = *(const uint4*)(Hc + row * HC_STR + q * 8);
                *(uint4*)(hio + (size_t)g * HH + q * 8) = v;
            }
        }
    }
}

// C4: out[n][o] = h . head_W[:,o] + head_b[o]; also predsc[n][o] = dinv11[n]*out
__global__ void head_kernel(const _Float16* __restrict__ hp, const float* __restrict__ headW,
                            const float* __restrict__ headb, const float* __restrict__ dinv11,
                            float* __restrict__ out, float* __restrict__ predsc) {
    int node = (blockIdx.x * 256 + threadIdx.x) >> 6;
    int lane = threadIdx.x & 63;
    if (node >= NN) return;
    const _Float16* h = hp + (size_t)node * HH;
    float h0 = (float)h[lane], h1 = (float)h[64 + lane];
    float s0 = h0 * headW[lane * 3 + 0] + h1 * headW[(64 + lane) * 3 + 0];
    float s1 = h0 * headW[lane * 3 + 1] + h1 * headW[(64 + lane) * 3 + 1];
    float s2 = h0 * headW[lane * 3 + 2] + h1 * headW[(64 + lane) * 3 + 2];
#pragma unroll
    for (int off = 32; off > 0; off >>= 1) {
        s0 += __shfl_down(s0, off);
        s1 += __shfl_down(s1, off);
        s2 += __shfl_down(s2, off);
    }
    if (lane == 0) {
        float o0 = s0 + headb[0], o1 = s1 + headb[1], o2 = s2 + headb[2];
        out[(size_t)node * 3 + 0] = o0;
        out[(size_t)node * 3 + 1] = o1;
        out[(size_t)node * 3 + 2] = o2;
        float dd = dinv11[node];
        predsc[(size_t)node * 4 + 0] = dd * o0;
        predsc[(size_t)node * 4 + 1] = dd * o1;
        predsc[(size_t)node * 4 + 2] = dd * o2;
    }
}

extern "C" void kernel_launch(void* const* d_in, const int* in_sizes, int n_in,
                              void* d_out, int out_size, void* d_ws, size_t ws_size,
                              hipStream_t stream) {
    const float* x = (const float*)d_in[0];
    const int* ei = (const int*)d_in[1];
    const float* ea = (const float*)d_in[2];
    const void* mask = d_in[3];
    const float* Wc[3] = {(const float*)d_in[4], (const float*)d_in[8], (const float*)d_in[12]};
    const float* bc[3] = {(const float*)d_in[5], (const float*)d_in[9], (const float*)d_in[13]};
    const float* Wl[3] = {(const float*)d_in[6], (const float*)d_in[10], (const float*)d_in[14]};
    const float* bl[3] = {(const float*)d_in[7], (const float*)d_in[11], (const float*)d_in[15]};
    const float* headW = (const float*)d_in[16];
    const float* headb = (const float*)d_in[17];
    float* out = (float*)d_out;

    char* w = (char*)d_ws;
    auto alloc = [&](size_t bytes) {
        char* p = w;
        w += (bytes + 255) & ~(size_t)255;
        return p;
    };
    float* dinv = (float*)alloc((size_t)TT * NN * 4);
    _Float16* xagg16 = (_Float16*)alloc((size_t)TT * NN * FF * 2);
    _Float16* xaggH16 = (_Float16*)alloc((size_t)NN * FF * 2);
    _Float16* xs16 = (_Float16*)alloc((size_t)TT * NN * FF * 2);
    int* chunkHist = (int*)alloc((size_t)TT * NBINS * NCH * 4);
    int* rowptr = (int*)alloc((size_t)TT * RP * 4);
    unsigned int* E1 = (unsigned int*)alloc((size_t)TT * EE * 4);  // compact CSR records
    uint2* E2 = (uint2*)alloc((size_t)6 * EE * 8);                 // staging, 6 slots (2 batches)
    _Float16* BcatT = (_Float16*)alloc((size_t)3 * HH * BKROW * 2);
    float* beff = (float*)alloc(3 * HH * 4);
    float* predsc = (float*)alloc((size_t)NN * 4 * 4);
    unsigned char* hm = (unsigned char*)alloc((size_t)TT * NN);
    unsigned char* mc = (unsigned char*)alloc((size_t)TT * NN);
    int* flag = (int*)alloc(64);

    // f16 horizon hidden state aliases the E2 staging area (dead after sortbin).
    _Float16* hph = (_Float16*)E2;   // 12.8 MB

    detect_mask<<<1, 256, 0, stream>>>((const unsigned char*)mask, flag);
    build_masks<<<(NN + 255) / 256, 256, 0, stream>>>(mask, flag, hm, mc);

    hist_kernel<<<dim3(NCH, TT), 256, 0, stream>>>(ei, chunkHist);
    scan_kernel<<<TT, 1024, 0, stream>>>(chunkHist);
    for (int b = 0; b < 2; b++) {
        scatter_kernel<<<dim3(NCH, 6), 256, 0, stream>>>(ei, ea, chunkHist, E2, b);
        sortbin_kernel<<<dim3(NBINS, 6), 256, 0, stream>>>(E2, chunkHist, E1, rowptr, dinv, b);
    }
    xs_kernel<<<TT * NN * 4 / 256, 256, 0, stream>>>(x, dinv, xs16);
    gather_csr<<<dim3((NN + 3) / 4, TT), 256, 0, stream>>>(E1, rowptr, dinv, xs16, xagg16);

    weight_kernel<<<3, 128, 0, stream>>>(Wc[0], bc[0], Wl[0], bl[0],
                                         Wc[1], bc[1], Wl[1], bl[1],
                                         Wc[2], bc[2], Wl[2], bl[2], BcatT, beff);

    // fused recurrent chain t=0..11: h resident in LDS, writes hph = mc11 ? h : 0
    cellseq_kernel<<<CGB, 512, 0, stream>>>(xagg16, hph, BcatT, beff, hm, mc, TT);

    hipMemcpyAsync(xaggH16, xagg16 + (size_t)11 * NN * FF, (size_t)NN * FF * 2,
                   hipMemcpyDeviceToDevice, stream);

    for (int k = 0; k < 6; k++) {
        const _Float16* xa = (k == 0) ? (xagg16 + (size_t)11 * NN * FF) : xaggH16;
        cellseq_kernel<<<CGB, 512, 0, stream>>>(xa, hph, BcatT, beff, nullptr, nullptr, 1);
        head_kernel<<<NN * 64 / 256, 256, 0, stream>>>(hph, headW, headb, dinv + (size_t)11 * NN,
                                                       out + (size_t)k * NN * 3, predsc);
        if (k < 5) {
            gather3_csr<<<(NN + 3) / 4, 256, 0, stream>>>(E1, rowptr, dinv, predsc, xaggH16);
        }
    }
}

// Round 6
// 1916.260 us; speedup vs baseline: 1.1194x; 1.0195x over previous
//
#include <hip/hip_runtime.h>
#include <math.h>

#define NN 50000
#define TT 12
#define EE 1600000
#define FF 16
#define HH 128
#define CHK 4096     // edges per chunk (level-1 histogram / scatter staging)
#define NCH 391      // ceil(EE/CHK)
#define BKT 128      // nodes per bin
#define NBINS 391    // ceil(NN/BKT) -> covers 50048
#define CAP 6144     // max edges per bin segment (mean 4096, sigma 64)
#define RP 50016     // rowptr stride per t (>= NN+1)
#define CGB 782      // ceil(NN/64) cell blocks
#define AR_STR 136   // rescaled-h LDS stride (halves): 272B rows
#define AX_STR 40    // x-part LDS stride (halves)
#define HC_STR 136   // committed-h LDS stride (halves)
#define BKROW 160    // BcatT row stride in halves: [h 0..127 | x 128..143 | zero 144..159]

typedef _Float16 half8_t __attribute__((ext_vector_type(8)));
typedef float floatx4 __attribute__((ext_vector_type(4)));

__device__ __forceinline__ float h16_to_f(unsigned short u) {
    _Float16 h; __builtin_memcpy(&h, &u, 2); return (float)h;
}
__device__ __forceinline__ unsigned short f_to_h16(float f) {
    _Float16 h = (_Float16)f; unsigned short u; __builtin_memcpy(&u, &h, 2); return u;
}
__device__ __forceinline__ float fsig(float x) {
    return 1.0f / (1.0f + exp2f(-1.44269504f * x));
}
__device__ __forceinline__ float ftanh(float x) {
    return 2.0f / (1.0f + exp2f(-2.88539009f * x)) - 1.0f;
}

// ---------------------------------------------------------------------------
// P0: detect mask dtype from byte pattern (uint8 / int32 / float32).
__global__ void detect_mask(const unsigned char* __restrict__ m, int* __restrict__ flag) {
    __shared__ int cnt[2];
    if (threadIdx.x < 2) cnt[threadIdx.x] = 0;
    __syncthreads();
    int a = 0, b = 0;
    for (int base = 0; base < 4096; base += 256) {
        int idx = base + threadIdx.x;
        unsigned char v = m[idx];
        int r = idx & 3;
        if (v) { if (r == 0) a++; else if (r == 1) b++; }
    }
    atomicAdd(&cnt[0], a);
    atomicAdd(&cnt[1], b);
    __syncthreads();
    if (threadIdx.x == 0) flag[0] = cnt[1] > 0 ? 0 : (cnt[0] > 0 ? 1 : 2);
}

// P1: hm[t][n] = mask & seen-before, mc[t][n] = mask
__global__ void build_masks(const void* __restrict__ mask, const int* __restrict__ flag,
                            unsigned char* __restrict__ hm, unsigned char* __restrict__ mc) {
    int n = blockIdx.x * 256 + threadIdx.x;
    if (n >= NN) return;
    int mode = flag[0];
    bool seen = false;
    for (int t = 0; t < TT; t++) {
        int idx = t * NN + n;
        bool m;
        if (mode == 0)      m = ((const unsigned char*)mask)[idx] != 0;
        else if (mode == 1) m = ((const int*)mask)[idx] != 0;
        else                m = ((const float*)mask)[idx] != 0.0f;
        hm[idx] = (m && seen) ? 1 : 0;
        mc[idx] = m ? 1 : 0;
        seen = seen || m;
    }
}

// ---------------------------------------------------------------------------
// S1: per-chunk histogram of dst bins (bin = dst>>7). layout [t][bin][chunk]
__global__ void hist_kernel(const int* __restrict__ ei, int* __restrict__ chunkHist) {
    __shared__ int h[NBINS + 1];
    int c = blockIdx.x, t = blockIdx.y, tid = threadIdx.x;
    for (int i = tid; i < NBINS; i += 256) h[i] = 0;
    __syncthreads();
    const int* dstp = ei + (size_t)(2 * t + 1) * EE;
    int e0 = c * CHK;
    for (int i = tid; i < CHK; i += 256) {
        int e = e0 + i;
        if (e < EE) atomicAdd(&h[dstp[e] >> 7], 1);
    }
    __syncthreads();
    for (int i = tid; i < NBINS; i += 256)
        chunkHist[((size_t)t * NBINS + i) * NCH + c] = h[i];
}

// S2: in-place exclusive scan of each t's [NBINS*NCH] array
__global__ void scan_kernel(int* __restrict__ buf) {
    __shared__ int ps[1024];
    const int L = NBINS * NCH;   // 152881
    const int PER = 150;         // 1024*150 >= L
    int t = blockIdx.x, tid = threadIdx.x;
    int* a = buf + (size_t)t * L;
    int i0 = tid * PER, i1 = min(i0 + PER, L);
    int s = 0;
    for (int i = i0; i < i1; i++) s += a[i];
    ps[tid] = s;
    __syncthreads();
    for (int off = 1; off < 1024; off <<= 1) {
        int v = (tid >= off) ? ps[tid - off] : 0;
        __syncthreads();
        ps[tid] += v;
        __syncthreads();
    }
    int base = (tid == 0) ? 0 : ps[tid - 1];
    for (int i = i0; i < i1; i++) { int v = a[i]; a[i] = base; base += v; }
}

// S3: LDS-staged scatter into bin-sorted order (batch of 6 t's).
// Record: uint2{src|dst<<16, w_f32}. Coalesced segment write-out.
__launch_bounds__(256)
__global__ void scatter_kernel(const int* __restrict__ ei, const float* __restrict__ ea,
                               const int* __restrict__ chunkOff, uint2* __restrict__ E2,
                               int batch) {
    __shared__ uint2 sorted[CHK];          // 32 KB
    __shared__ int cnt[NBINS];
    __shared__ int sA[NBINS], sB[NBINS];
    __shared__ int start[NBINS], gbase[NBINS];
    int c = blockIdx.x, y = blockIdx.y, tid = threadIdx.x;
    int t = batch * 6 + y;
    for (int i = tid; i < NBINS; i += 256) {
        cnt[i] = 0;
        gbase[i] = chunkOff[((size_t)t * NBINS + i) * NCH + c];
    }
    __syncthreads();
    const int* srcp = ei + (size_t)(2 * t) * EE;
    const int* dstp = ei + (size_t)(2 * t + 1) * EE;
    const float* wp = ea + (size_t)t * EE;
    int e0 = c * CHK;
    int m = min(CHK, EE - e0);
    uint2 rec[16];
    int rank[16];
#pragma unroll
    for (int k = 0; k < 16; k++) {
        int i = k * 256 + tid;
        rank[k] = -1;
        if (i < m) {
            int e = e0 + i;
            unsigned int s = (unsigned int)srcp[e];
            unsigned int d = (unsigned int)dstp[e];
            float wv = wp[e];
            rec[k].x = s | (d << 16);
            rec[k].y = __float_as_uint(wv);
            rank[k] = atomicAdd(&cnt[d >> 7], 1);
        }
    }
    __syncthreads();
    for (int i = tid; i < NBINS; i += 256) sA[i] = cnt[i];
    __syncthreads();
    int pp = 0;
    for (int off = 1; off < NBINS; off <<= 1) {
        if (pp == 0) {
            for (int i = tid; i < NBINS; i += 256)
                sB[i] = (i >= off) ? sA[i] + sA[i - off] : sA[i];
        } else {
            for (int i = tid; i < NBINS; i += 256)
                sA[i] = (i >= off) ? sB[i] + sB[i - off] : sB[i];
        }
        pp ^= 1;
        __syncthreads();
    }
    const int* inc = pp ? sB : sA;
    for (int i = tid; i < NBINS; i += 256) start[i] = inc[i] - cnt[i];
    __syncthreads();
#pragma unroll
    for (int k = 0; k < 16; k++) {
        if (rank[k] >= 0) {
            int b = rec[k].x >> 23;
            sorted[start[b] + rank[k]] = rec[k];
        }
    }
    __syncthreads();
    uint2* outp = E2 + (size_t)y * EE;
    for (int i = tid; i < m; i += 256) {
        uint2 r = sorted[i];
        int b = r.x >> 23;
        outp[gbase[b] + (i - start[b])] = r;
    }
}

// S4: per-bin counting sort -> compact CSR records (src u16 | w'=w*dinv[d] f16)
// + rowptr + dinv. Reads uint2 staging E2, writes 4B records to E1.
__launch_bounds__(256)
__global__ void sortbin_kernel(const uint2* __restrict__ E2, const int* __restrict__ chunkHist,
                               unsigned int* __restrict__ E1, int* __restrict__ rowptr,
                               float* __restrict__ dinvG, int batch) {
    __shared__ uint2 es[CAP];   // 48 KB
    __shared__ int cnt[BKT];
    __shared__ float wsm[BKT];
    __shared__ int cur[BKT];
    int b = blockIdx.x, y = blockIdx.y, tid = threadIdx.x;
    int t = batch * 6 + y;
    const uint2* gE = E2 + (size_t)y * EE;
    unsigned int* oE = E1 + (size_t)t * EE;
    const int* off = chunkHist + (size_t)t * NBINS * NCH;
    int e0 = off[b * NCH];
    int e1 = (b == NBINS - 1) ? EE : off[(b + 1) * NCH];
    int seg = e1 - e0;
    for (int i = tid; i < seg; i += 256) es[i] = gE[e0 + i];
    if (tid < BKT) { cnt[tid] = 0; wsm[tid] = 0.0f; }
    __syncthreads();
    for (int i = tid; i < seg; i += 256) {
        int dl = (es[i].x >> 16) & 127;
        atomicAdd(&cnt[dl], 1);
        atomicAdd(&wsm[dl], __uint_as_float(es[i].y));
    }
    __syncthreads();
    int ogv = (tid < BKT) ? cnt[tid] : 0;
    for (int o = 1; o < BKT; o <<= 1) {
        int u = (tid < BKT && tid >= o) ? cnt[tid - o] : 0;
        __syncthreads();
        if (tid < BKT) cnt[tid] += u;
        __syncthreads();
    }
    if (tid < BKT) {
        int exc = cnt[tid] - ogv;
        cur[tid] = exc;
        float dv = rsqrtf(1.0f + wsm[tid]);
        wsm[tid] = dv;   // reuse as dinv-local
        int node = b * BKT + tid;
        if (node <= NN) {
            rowptr[(size_t)t * RP + node] = e0 + exc;
            if (node < NN) dinvG[(size_t)t * NN + node] = dv;
        }
    }
    __syncthreads();
    for (int i = tid; i < seg; i += 256) {
        uint2 p = es[i];
        int dl = (p.x >> 16) & 127;
        int pos = atomicAdd(&cur[dl], 1);
        float wv = __uint_as_float(p.y) * wsm[dl];
        oE[e0 + pos] = (p.x & 0xFFFF) | ((unsigned int)f_to_h16(wv) << 16);
    }
}

// S4b: xs[t][n][f] = (f16)(dinv[t][n] * x[t][n][f])
__global__ void xs_kernel(const float* __restrict__ x, const float* __restrict__ dinvG,
                          _Float16* __restrict__ xs16) {
    int gid = blockIdx.x * 256 + threadIdx.x;   // TT*NN*4 float4 groups (exact: 9375 blocks)
    int tn = gid >> 2;
    float dd = dinvG[tn];
    float4 v = ((const float4*)x)[gid];
    _Float16 h[4] = {(_Float16)(dd * v.x), (_Float16)(dd * v.y),
                     (_Float16)(dd * v.z), (_Float16)(dd * v.w)};
    uint2 o;
    __builtin_memcpy(&o, h, 8);
    ((uint2*)xs16)[gid] = o;
}

// S5: CSR gather: wave per (t,node). 2-way software-pipelined edge loop:
// two independent rec->xs dependency chains per iteration (MLP 2x on the
// L2-latency-bound path).
__global__ void gather_csr(const unsigned int* __restrict__ E1, const int* __restrict__ rowptr,
                           const float* __restrict__ dinvG, const _Float16* __restrict__ xs16,
                           _Float16* __restrict__ xagg16) {
    int t = blockIdx.y;
    int n = blockIdx.x * 4 + (threadIdx.x >> 6);
    if (n >= NN) return;
    int lane = threadIdx.x & 63;
    int eo = lane >> 3, fp = lane & 7;
    const unsigned int* gE = E1 + (size_t)t * EE;
    const _Float16* xs = xs16 + (size_t)t * NN * FF;
    int r0 = rowptr[(size_t)t * RP + n], r1 = rowptr[(size_t)t * RP + n + 1];
    float a0 = 0.0f, a1 = 0.0f;
    int e = r0 + eo;
    for (; e + 8 < r1; e += 16) {
        unsigned int recA = gE[e];
        unsigned int recB = gE[e + 8];
        unsigned int xpA = *(const unsigned int*)(xs + (size_t)(recA & 0xFFFF) * FF + 2 * fp);
        unsigned int xpB = *(const unsigned int*)(xs + (size_t)(recB & 0xFFFF) * FF + 2 * fp);
        float wA = h16_to_f((unsigned short)(recA >> 16));
        float wB = h16_to_f((unsigned short)(recB >> 16));
        a0 += wA * h16_to_f((unsigned short)(xpA & 0xFFFF));
        a1 += wA * h16_to_f((unsigned short)(xpA >> 16));
        a0 += wB * h16_to_f((unsigned short)(xpB & 0xFFFF));
        a1 += wB * h16_to_f((unsigned short)(xpB >> 16));
    }
    if (e < r1) {
        unsigned int rec = gE[e];
        float wv = h16_to_f((unsigned short)(rec >> 16));
        unsigned int xp = *(const unsigned int*)(xs + (size_t)(rec & 0xFFFF) * FF + 2 * fp);
        a0 += wv * h16_to_f((unsigned short)(xp & 0xFFFF));
        a1 += wv * h16_to_f((unsigned short)(xp >> 16));
    }
    a0 += __shfl_xor(a0, 8);  a1 += __shfl_xor(a1, 8);
    a0 += __shfl_xor(a0, 16); a1 += __shfl_xor(a1, 16);
    a0 += __shfl_xor(a0, 32); a1 += __shfl_xor(a1, 32);
    if (eo == 0) {
        float dd = dinvG[(size_t)t * NN + n];
        unsigned int xp = *(const unsigned int*)(xs + (size_t)n * FF + 2 * fp);
        float o0 = a0 + dd * h16_to_f((unsigned short)(xp & 0xFFFF));
        float o1 = a1 + dd * h16_to_f((unsigned short)(xp >> 16));
        unsigned int pack = (unsigned int)f_to_h16(o0) | ((unsigned int)f_to_h16(o1) << 16);
        ((unsigned int*)(xagg16 + ((size_t)t * NN + n) * FF))[fp] = pack;
    }
}

// S6 (horizon): 3-feature CSR re-aggregation of predsc over t=11, 2-way MLP.
__global__ void gather3_csr(const unsigned int* __restrict__ E1, const int* __restrict__ rowptr,
                            const float* __restrict__ dinvG, const float* __restrict__ predsc,
                            _Float16* __restrict__ xaggH16) {
    int n = blockIdx.x * 4 + (threadIdx.x >> 6);
    if (n >= NN) return;
    int lane = threadIdx.x & 63;
    int eo = lane >> 2, f = lane & 3;
    const unsigned int* gE = E1 + (size_t)11 * EE;
    const float* dv = dinvG + (size_t)11 * NN;
    int r0 = rowptr[(size_t)11 * RP + n], r1 = rowptr[(size_t)11 * RP + n + 1];
    float acc = 0.0f;
    int e = r0 + eo;
    for (; e + 16 < r1; e += 32) {
        unsigned int recA = gE[e];
        unsigned int recB = gE[e + 16];
        if (f < 3) {
            float pA = predsc[(size_t)(recA & 0xFFFF) * 4 + f];
            float pB = predsc[(size_t)(recB & 0xFFFF) * 4 + f];
            acc += h16_to_f((unsigned short)(recA >> 16)) * pA;
            acc += h16_to_f((unsigned short)(recB >> 16)) * pB;
        }
    }
    if (e < r1) {
        unsigned int rec = gE[e];
        if (f < 3)
            acc += h16_to_f((unsigned short)(rec >> 16)) * predsc[(size_t)(rec & 0xFFFF) * 4 + f];
    }
    acc += __shfl_xor(acc, 4);
    acc += __shfl_xor(acc, 8);
    acc += __shfl_xor(acc, 16);
    acc += __shfl_xor(acc, 32);
    if (lane < 3) {
        float res = acc + dv[n] * predsc[(size_t)n * 4 + f];
        xaggH16[(size_t)n * FF + f] = (_Float16)res;
    }
}

// ---------------------------------------------------------------------------
// W: fold Wc into Wl_top -> BcatT[g][n=128][k: h(0..127) | x(128..143) | 0(144..159)]
__global__ void weight_kernel(const float* Wc0, const float* bc0, const float* Wl0, const float* bl0,
                              const float* Wc1, const float* bc1, const float* Wl1, const float* bl1,
                              const float* Wc2, const float* bc2, const float* Wl2, const float* bl2,
                              _Float16* __restrict__ BcatT, float* __restrict__ beff) {
    __shared__ float WcS[FF][HH];
    int g = blockIdx.x;
    int n = threadIdx.x;  // 128
    const float* Wc = g == 0 ? Wc0 : (g == 1 ? Wc1 : Wc2);
    const float* bc = g == 0 ? bc0 : (g == 1 ? bc1 : bc2);
    const float* Wl = g == 0 ? Wl0 : (g == 1 ? Wl1 : Wl2);
    const float* bl = g == 0 ? bl0 : (g == 1 ? bl1 : bl2);
    for (int q = 0; q < FF; q++) WcS[q][n] = Wc[q * HH + n];
    __syncthreads();
    float acc[FF];
#pragma unroll
    for (int i = 0; i < FF; i++) acc[i] = 0.0f;
    float accb = 0.0f;
    for (int k = 0; k < HH; k++) {
        float wl = Wl[k * HH + n];
        accb += bc[k] * wl;
#pragma unroll
        for (int i = 0; i < FF; i++) acc[i] += WcS[i][k] * wl;
    }
    _Float16* row = BcatT + ((size_t)g * HH + n) * BKROW;
    for (int j = 0; j < HH; j++) row[j] = (_Float16)Wl[(size_t)(HH + j) * HH + n];
#pragma unroll
    for (int i = 0; i < FF; i++) row[HH + i] = (_Float16)acc[i];
#pragma unroll
    for (int i = 144; i < 160; i++) row[i] = (_Float16)0.0f;
    beff[g * HH + n] = bl[n] + accb;
}

// ---------------------------------------------------------------------------
// CELLSEQ v4: fused multi-step GRU cell, transposed MFMA, weights in regs,
// NO Ah staging buffer: phase A reads MFMA fragments DIRECTLY from Hc and
// applies the hm mask per-lane with cndmask (mask is per node = per B-col).
//  - LDS: Hc + Ar + Ax = 39936 B (was 57344).
//  - 3 barriers/step; ~35 KB/block-step less LDS traffic.
//  - single mode: stage hio->Hc once, mask=true, epilogue writes hio direct.
__launch_bounds__(512, 2)
__global__ void cellseq_kernel(const _Float16* __restrict__ xaggBase,
                               _Float16* __restrict__ hio,
                               const _Float16* __restrict__ BcatT,
                               const float* __restrict__ beff,
                               const unsigned char* __restrict__ hmAll,
                               const unsigned char* __restrict__ mcAll,
                               int nsteps) {
    __shared__ _Float16 Hc[64 * HC_STR];   // 17408 B : committed h
    __shared__ _Float16 Ar[64 * AR_STR];   // 17408 B : rescaled h (h * sig(r))
    __shared__ _Float16 Ax[64 * AX_STR];   //  5120 B : x-part (k 128..143) + zero pad
    const int tid = threadIdx.x;           // 0..511
    const int m0 = blockIdx.x * 64;
    const int lane = tid & 63;
    const int w = tid >> 6;                // 0..7
    const int mrow = lane & 15;
    const int quad = lane >> 4;
    const int col0 = w * 16;
    const int cb = col0 + quad * 4;        // this lane's 4 output cols
    const bool rec = (hmAll != nullptr);

    // persistent per-lane biases (own 4 cols)
    const float4 bz4 = *(const float4*)(beff + cb);
    const float4 br4 = *(const float4*)(beff + HH + cb);
    const float4 bh4 = *(const float4*)(beff + 2 * HH + cb);

    // persistent weight fragments for ALL gates (A-operand rows = col0+mrow)
    const _Float16* Wzp = BcatT + (size_t)(col0 + mrow) * BKROW + quad * 8;
    half8_t wz[5], wr[5], wh[5];
#pragma unroll
    for (int ks = 0; ks < 5; ks++) {
        wz[ks] = *(const half8_t*)(Wzp + ks * 32);
        wr[ks] = *(const half8_t*)(Wzp + (size_t)HH * BKROW + ks * 32);
        wh[ks] = *(const half8_t*)(Wzp + (size_t)2 * HH * BKROW + ks * 32);
    }

    // zero Ax pad (k 144..159, never rewritten).
    for (int idx = tid; idx < 128; idx += 512) {
        int row = idx >> 1, q = idx & 1;
        *(uint4*)(Ax + row * AX_STR + 16 + q * 8) = make_uint4(0, 0, 0, 0);
    }
    // init Hc: rec -> zero; single -> stage hio
    for (int idx = tid; idx < 1024; idx += 512) {
        int row = idx >> 4, q = idx & 15;
        int g = m0 + row;
        uint4 v = make_uint4(0, 0, 0, 0);
        if (!rec && g < NN) v = *(const uint4*)(hio + (size_t)g * HH + q * 8);
        *(uint4*)(Hc + row * HC_STR + q * 8) = v;
    }
    __syncthreads();

    const half8_t h8z = {0, 0, 0, 0, 0, 0, 0, 0};

    for (int t = 0; t < nsteps; t++) {
        const _Float16* xa = xaggBase + (size_t)t * NN * FF;
        const unsigned char* hm = rec ? (hmAll + (size_t)t * NN) : nullptr;
        const unsigned char* mc = rec ? (mcAll + (size_t)t * NN) : nullptr;

        // ---- build Ax only (Hc read directly in phase A) ----
        for (int idx = tid; idx < 128; idx += 512) {
            int row = idx >> 1, q = idx & 1;
            int g = m0 + row;
            uint4 v = make_uint4(0, 0, 0, 0);
            if (g < NN) v = *(const uint4*)(xa + (size_t)g * FF + q * 8);
            *(uint4*)(Ax + row * AX_STR + q * 8) = v;
        }
        __syncthreads();   // bar1: Ax ready, Hc stable from prev step

        // ---- phase A: z and r MFMAs from masked Hc + rescale -> Ar ----
        floatx4 zacc[4];
        unsigned int hpw[4][2];   // masked hprev (own 4 cols per node-tile)
#pragma unroll
        for (int nt = 0; nt < 4; nt++) {
            int node = nt * 16 + mrow;
            int g = m0 + node;
            bool m = (g < NN) && (!rec || hm[g] != 0);
            const _Float16* hp = Hc + node * HC_STR;
            half8_t hx[5];
#pragma unroll
            for (int ks = 0; ks < 4; ks++) {
                half8_t v = *(const half8_t*)(hp + ks * 32 + quad * 8);
                hx[ks] = m ? v : h8z;
            }
            hx[4] = *(const half8_t*)(Ax + node * AX_STR + quad * 8);
            floatx4 za = {0.0f, 0.0f, 0.0f, 0.0f}, ra = {0.0f, 0.0f, 0.0f, 0.0f};
#pragma unroll
            for (int ks = 0; ks < 5; ks++)
                za = __builtin_amdgcn_mfma_f32_16x16x32_f16(wz[ks], hx[ks], za, 0, 0, 0);
#pragma unroll
            for (int ks = 0; ks < 5; ks++)
                ra = __builtin_amdgcn_mfma_f32_16x16x32_f16(wr[ks], hx[ks], ra, 0, 0, 0);
            zacc[nt] = za;
            // masked hprev for own (node, cols cb..cb+3): one b64 read + select
            uint2 hpr = *(const uint2*)(hp + cb);
            uint2 hpv = m ? hpr : make_uint2(0, 0);
            hpw[nt][0] = hpv.x; hpw[nt][1] = hpv.y;
            float r0 = fsig(ra[0] + br4.x), r1 = fsig(ra[1] + br4.y);
            float r2 = fsig(ra[2] + br4.z), r3 = fsig(ra[3] + br4.w);
            float hp0 = h16_to_f((unsigned short)(hpv.x & 0xFFFF));
            float hp1 = h16_to_f((unsigned short)(hpv.x >> 16));
            float hp2 = h16_to_f((unsigned short)(hpv.y & 0xFFFF));
            float hp3 = h16_to_f((unsigned short)(hpv.y >> 16));
            uint2 o;
            o.x = (unsigned int)f_to_h16(hp0 * r0) | ((unsigned int)f_to_h16(hp1 * r1) << 16);
            o.y = (unsigned int)f_to_h16(hp2 * r2) | ((unsigned int)f_to_h16(hp3 * r3) << 16);
            *(uint2*)(Ar + node * AR_STR + cb) = o;
        }
        __syncthreads();   // bar2: Ar complete, Hc reads of this step done

        // ---- phase B: h~ MFMAs from Ar|Ax + epilogue -> Hc / hio ----
#pragma unroll
        for (int nt = 0; nt < 4; nt++) {
            int node = nt * 16 + mrow;
            const _Float16* ap = Ar + node * AR_STR;
            half8_t hx[5];
#pragma unroll
            for (int ks = 0; ks < 4; ks++) hx[ks] = *(const half8_t*)(ap + ks * 32 + quad * 8);
            hx[4] = *(const half8_t*)(Ax + node * AX_STR + quad * 8);
            floatx4 ha = {0.0f, 0.0f, 0.0f, 0.0f};
#pragma unroll
            for (int ks = 0; ks < 5; ks++)
                ha = __builtin_amdgcn_mfma_f32_16x16x32_f16(wh[ks], hx[ks], ha, 0, 0, 0);
            int g = m0 + node;
            if (g < NN) {
                float z0 = fsig(zacc[nt][0] + bz4.x), z1 = fsig(zacc[nt][1] + bz4.y);
                float z2 = fsig(zacc[nt][2] + bz4.z), z3 = fsig(zacc[nt][3] + bz4.w);
                float t0 = ftanh(ha[0] + bh4.x), t1 = ftanh(ha[1] + bh4.y);
                float t2 = ftanh(ha[2] + bh4.z), t3 = ftanh(ha[3] + bh4.w);
                float hp0 = h16_to_f((unsigned short)(hpw[nt][0] & 0xFFFF));
                float hp1 = h16_to_f((unsigned short)(hpw[nt][0] >> 16));
                float hp2 = h16_to_f((unsigned short)(hpw[nt][1] & 0xFFFF));
                float hp3 = h16_to_f((unsigned short)(hpw[nt][1] >> 16));
                float n0 = z0 * hp0 + (1.0f - z0) * t0;
                float n1 = z1 * hp1 + (1.0f - z1) * t1;
                float n2 = z2 * hp2 + (1.0f - z2) * t2;
                float n3 = z3 * hp3 + (1.0f - z3) * t3;
                uint2 o;
                o.x = (unsigned int)f_to_h16(n0) | ((unsigned int)f_to_h16(n1) << 16);
                o.y = (unsigned int)f_to_h16(n2) | ((unsigned int)f_to_h16(n3) << 16);
                if (rec) {
                    if (mc[g]) *(uint2*)(Hc + node * HC_STR + cb) = o;
                } else {
                    *(uint2*)(hio + (size_t)g * HH + cb) = o;
                }
            }
        }
        __syncthreads();   // bar3: Hc committed / Ar+Ax readers done
    }

    // ---- final (rec only): hio = mc[last] ? Hc : 0 ----
    if (rec) {
        const unsigned char* mcL = mcAll + (size_t)(nsteps - 1) * NN;
        for (int idx = tid; idx < 1024; idx += 512) {
            int row = idx >> 4, q = idx & 15;
            int g = m0 + row;
            if (g < NN) {
                uint4 v = make_uint4(0, 0, 0, 0);
                if (mcL[g]) v = *(const uint4*)(Hc + row * HC_STR + q * 8);
                *(uint4*)(hio + (size_t)g * HH + q * 8) = v;
            }
        }
    }
}

// C4: out[n][o] = h . head_W[:,o] + head_b[o]; also predsc[n][o] = dinv11[n]*out
__global__ void head_kernel(const _Float16* __restrict__ hp, const float* __restrict__ headW,
                            const float* __restrict__ headb, const float* __restrict__ dinv11,
                            float* __restrict__ out, float* __restrict__ predsc) {
    int node = (blockIdx.x * 256 + threadIdx.x) >> 6;
    int lane = threadIdx.x & 63;
    if (node >= NN) return;
    const _Float16* h = hp + (size_t)node * HH;
    float h0 = (float)h[lane], h1 = (float)h[64 + lane];
    float s0 = h0 * headW[lane * 3 + 0] + h1 * headW[(64 + lane) * 3 + 0];
    float s1 = h0 * headW[lane * 3 + 1] + h1 * headW[(64 + lane) * 3 + 1];
    float s2 = h0 * headW[lane * 3 + 2] + h1 * headW[(64 + lane) * 3 + 2];
#pragma unroll
    for (int off = 32; off > 0; off >>= 1) {
        s0 += __shfl_down(s0, off);
        s1 += __shfl_down(s1, off);
        s2 += __shfl_down(s2, off);
    }
    if (lane == 0) {
        float o0 = s0 + headb[0], o1 = s1 + headb[1], o2 = s2 + headb[2];
        out[(size_t)node * 3 + 0] = o0;
        out[(size_t)node * 3 + 1] = o1;
        out[(size_t)node * 3 + 2] = o2;
        float dd = dinv11[node];
        predsc[(size_t)node * 4 + 0] = dd * o0;
        predsc[(size_t)node * 4 + 1] = dd * o1;
        predsc[(size_t)node * 4 + 2] = dd * o2;
    }
}

extern "C" void kernel_launch(void* const* d_in, const int* in_sizes, int n_in,
                              void* d_out, int out_size, void* d_ws, size_t ws_size,
                              hipStream_t stream) {
    const float* x = (const float*)d_in[0];
    const int* ei = (const int*)d_in[1];
    const float* ea = (const float*)d_in[2];
    const void* mask = d_in[3];
    const float* Wc[3] = {(const float*)d_in[4], (const float*)d_in[8], (const float*)d_in[12]};
    const float* bc[3] = {(const float*)d_in[5], (const float*)d_in[9], (const float*)d_in[13]};
    const float* Wl[3] = {(const float*)d_in[6], (const float*)d_in[10], (const float*)d_in[14]};
    const float* bl[3] = {(const float*)d_in[7], (const float*)d_in[11], (const float*)d_in[15]};
    const float* headW = (const float*)d_in[16];
    const float* headb = (const float*)d_in[17];
    float* out = (float*)d_out;

    char* w = (char*)d_ws;
    auto alloc = [&](size_t bytes) {
        char* p = w;
        w += (bytes + 255) & ~(size_t)255;
        return p;
    };
    float* dinv = (float*)alloc((size_t)TT * NN * 4);
    _Float16* xagg16 = (_Float16*)alloc((size_t)TT * NN * FF * 2);
    _Float16* xaggH16 = (_Float16*)alloc((size_t)NN * FF * 2);
    _Float16* xs16 = (_Float16*)alloc((size_t)TT * NN * FF * 2);
    int* chunkHist = (int*)alloc((size_t)TT * NBINS * NCH * 4);
    int* rowptr = (int*)alloc((size_t)TT * RP * 4);
    unsigned int* E1 = (unsigned int*)alloc((size_t)TT * EE * 4);  // compact CSR records
    uint2* E2 = (uint2*)alloc((size_t)6 * EE * 8);                 // staging, 6 slots (2 batches)
    _Float16* BcatT = (_Float16*)alloc((size_t)3 * HH * BKROW * 2);
    float* beff = (float*)alloc(3 * HH * 4);
    float* predsc = (float*)alloc((size_t)NN * 4 * 4);
    unsigned char* hm = (unsigned char*)alloc((size_t)TT * NN);
    unsigned char* mc = (unsigned char*)alloc((size_t)TT * NN);
    int* flag = (int*)alloc(64);

    // f16 horizon hidden state aliases the E2 staging area (dead after sortbin).
    _Float16* hph = (_Float16*)E2;   // 12.8 MB

    detect_mask<<<1, 256, 0, stream>>>((const unsigned char*)mask, flag);
    build_masks<<<(NN + 255) / 256, 256, 0, stream>>>(mask, flag, hm, mc);

    hist_kernel<<<dim3(NCH, TT), 256, 0, stream>>>(ei, chunkHist);
    scan_kernel<<<TT, 1024, 0, stream>>>(chunkHist);
    for (int b = 0; b < 2; b++) {
        scatter_kernel<<<dim3(NCH, 6), 256, 0, stream>>>(ei, ea, chunkHist, E2, b);
        sortbin_kernel<<<dim3(NBINS, 6), 256, 0, stream>>>(E2, chunkHist, E1, rowptr, dinv, b);
    }
    xs_kernel<<<TT * NN * 4 / 256, 256, 0, stream>>>(x, dinv, xs16);
    gather_csr<<<dim3((NN + 3) / 4, TT), 256, 0, stream>>>(E1, rowptr, dinv, xs16, xagg16);

    weight_kernel<<<3, 128, 0, stream>>>(Wc[0], bc[0], Wl[0], bl[0],
                                         Wc[1], bc[1], Wl[1], bl[1],
                                         Wc[2], bc[2], Wl[2], bl[2], BcatT, beff);

    // fused recurrent chain t=0..11: h resident in LDS, writes hph = mc11 ? h : 0
    cellseq_kernel<<<CGB, 512, 0, stream>>>(xagg16, hph, BcatT, beff, hm, mc, TT);

    hipMemcpyAsync(xaggH16, xagg16 + (size_t)11 * NN * FF, (size_t)NN * FF * 2,
                   hipMemcpyDeviceToDevice, stream);

    for (int k = 0; k < 6; k++) {
        const _Float16* xa = (k == 0) ? (xagg16 + (size_t)11 * NN * FF) : xaggH16;
        cellseq_kernel<<<CGB, 512, 0, stream>>>(xa, hph, BcatT, beff, nullptr, nullptr, 1);
        head_kernel<<<NN * 64 / 256, 256, 0, stream>>>(hph, headW, headb, dinv + (size_t)11 * NN,
                                                       out + (size_t)k * NN * 3, predsc);
        if (k < 5) {
            gather3_csr<<<(NN + 3) / 4, 256, 0, stream>>>(E1, rowptr, dinv, predsc, xaggH16);
        }
    }
}

// Round 7
// 1880.572 us; speedup vs baseline: 1.1406x; 1.0190x over previous
//
#include <hip/hip_runtime.h>
#include <math.h>

#define NN 50000
#define TT 12
#define EE 1600000
#define FF 16
#define HH 128
#define CHK 4096     // edges per chunk (level-1 histogram / scatter staging)
#define NCH 391      // ceil(EE/CHK)
#define BKT 128      // nodes per bin
#define NBINS 391    // ceil(NN/BKT) -> covers 50048
#define CAP 6144     // max edges per bin segment (mean 4096, sigma 64)
#define RP 50016     // rowptr stride per t (>= NN+1)
#define CGB 782      // ceil(NN/64) cell blocks
#define H_STR 136    // h LDS stride (halves): 272B rows
#define AR_STR 136   // rescaled-h LDS stride
#define AX_STR 40    // x-part LDS stride (halves)
#define BKROW 160    // BcatT row stride in halves: [h 0..127 | x 128..143 | zero 144..159]

typedef _Float16 half8_t __attribute__((ext_vector_type(8)));
typedef float floatx4 __attribute__((ext_vector_type(4)));

__device__ __forceinline__ float h16_to_f(unsigned short u) {
    _Float16 h; __builtin_memcpy(&h, &u, 2); return (float)h;
}
__device__ __forceinline__ unsigned short f_to_h16(float f) {
    _Float16 h = (_Float16)f; unsigned short u; __builtin_memcpy(&u, &h, 2); return u;
}
__device__ __forceinline__ float fsig(float x) {
    return 1.0f / (1.0f + exp2f(-1.44269504f * x));
}
__device__ __forceinline__ float ftanh(float x) {
    return 2.0f / (1.0f + exp2f(-2.88539009f * x)) - 1.0f;
}

// ---------------------------------------------------------------------------
// P0: detect mask dtype from byte pattern (uint8 / int32 / float32).
__global__ void detect_mask(const unsigned char* __restrict__ m, int* __restrict__ flag) {
    __shared__ int cnt[2];
    if (threadIdx.x < 2) cnt[threadIdx.x] = 0;
    __syncthreads();
    int a = 0, b = 0;
    for (int base = 0; base < 4096; base += 256) {
        int idx = base + threadIdx.x;
        unsigned char v = m[idx];
        int r = idx & 3;
        if (v) { if (r == 0) a++; else if (r == 1) b++; }
    }
    atomicAdd(&cnt[0], a);
    atomicAdd(&cnt[1], b);
    __syncthreads();
    if (threadIdx.x == 0) flag[0] = cnt[1] > 0 ? 0 : (cnt[0] > 0 ? 1 : 2);
}

// P1: hm[t][n] = mask & seen-before, mc[t][n] = mask
__global__ void build_masks(const void* __restrict__ mask, const int* __restrict__ flag,
                            unsigned char* __restrict__ hm, unsigned char* __restrict__ mc) {
    int n = blockIdx.x * 256 + threadIdx.x;
    if (n >= NN) return;
    int mode = flag[0];
    bool seen = false;
    for (int t = 0; t < TT; t++) {
        int idx = t * NN + n;
        bool m;
        if (mode == 0)      m = ((const unsigned char*)mask)[idx] != 0;
        else if (mode == 1) m = ((const int*)mask)[idx] != 0;
        else                m = ((const float*)mask)[idx] != 0.0f;
        hm[idx] = (m && seen) ? 1 : 0;
        mc[idx] = m ? 1 : 0;
        seen = seen || m;
    }
}

// ---------------------------------------------------------------------------
// S1: per-chunk histogram of dst bins (bin = dst>>7). layout [t][bin][chunk]
__global__ void hist_kernel(const int* __restrict__ ei, int* __restrict__ chunkHist) {
    __shared__ int h[NBINS + 1];
    int c = blockIdx.x, t = blockIdx.y, tid = threadIdx.x;
    for (int i = tid; i < NBINS; i += 256) h[i] = 0;
    __syncthreads();
    const int* dstp = ei + (size_t)(2 * t + 1) * EE;
    int e0 = c * CHK;
    for (int i = tid; i < CHK; i += 256) {
        int e = e0 + i;
        if (e < EE) atomicAdd(&h[dstp[e] >> 7], 1);
    }
    __syncthreads();
    for (int i = tid; i < NBINS; i += 256)
        chunkHist[((size_t)t * NBINS + i) * NCH + c] = h[i];
}

// S2: in-place exclusive scan of each t's [NBINS*NCH] array
__global__ void scan_kernel(int* __restrict__ buf) {
    __shared__ int ps[1024];
    const int L = NBINS * NCH;   // 152881
    const int PER = 150;         // 1024*150 >= L
    int t = blockIdx.x, tid = threadIdx.x;
    int* a = buf + (size_t)t * L;
    int i0 = tid * PER, i1 = min(i0 + PER, L);
    int s = 0;
    for (int i = i0; i < i1; i++) s += a[i];
    ps[tid] = s;
    __syncthreads();
    for (int off = 1; off < 1024; off <<= 1) {
        int v = (tid >= off) ? ps[tid - off] : 0;
        __syncthreads();
        ps[tid] += v;
        __syncthreads();
    }
    int base = (tid == 0) ? 0 : ps[tid - 1];
    for (int i = i0; i < i1; i++) { int v = a[i]; a[i] = base; base += v; }
}

// S3: LDS-staged scatter into bin-sorted order (batch of 6 t's).
// Record: uint2{src|dst<<16, w_f32}. Coalesced segment write-out.
__launch_bounds__(256)
__global__ void scatter_kernel(const int* __restrict__ ei, const float* __restrict__ ea,
                               const int* __restrict__ chunkOff, uint2* __restrict__ E2,
                               int batch) {
    __shared__ uint2 sorted[CHK];          // 32 KB
    __shared__ int cnt[NBINS];
    __shared__ int sA[NBINS], sB[NBINS];
    __shared__ int start[NBINS], gbase[NBINS];
    int c = blockIdx.x, y = blockIdx.y, tid = threadIdx.x;
    int t = batch * 6 + y;
    for (int i = tid; i < NBINS; i += 256) {
        cnt[i] = 0;
        gbase[i] = chunkOff[((size_t)t * NBINS + i) * NCH + c];
    }
    __syncthreads();
    const int* srcp = ei + (size_t)(2 * t) * EE;
    const int* dstp = ei + (size_t)(2 * t + 1) * EE;
    const float* wp = ea + (size_t)t * EE;
    int e0 = c * CHK;
    int m = min(CHK, EE - e0);
    uint2 rec[16];
    int rank[16];
#pragma unroll
    for (int k = 0; k < 16; k++) {
        int i = k * 256 + tid;
        rank[k] = -1;
        if (i < m) {
            int e = e0 + i;
            unsigned int s = (unsigned int)srcp[e];
            unsigned int d = (unsigned int)dstp[e];
            float wv = wp[e];
            rec[k].x = s | (d << 16);
            rec[k].y = __float_as_uint(wv);
            rank[k] = atomicAdd(&cnt[d >> 7], 1);
        }
    }
    __syncthreads();
    for (int i = tid; i < NBINS; i += 256) sA[i] = cnt[i];
    __syncthreads();
    int pp = 0;
    for (int off = 1; off < NBINS; off <<= 1) {
        if (pp == 0) {
            for (int i = tid; i < NBINS; i += 256)
                sB[i] = (i >= off) ? sA[i] + sA[i - off] : sA[i];
        } else {
            for (int i = tid; i < NBINS; i += 256)
                sA[i] = (i >= off) ? sB[i] + sB[i - off] : sB[i];
        }
        pp ^= 1;
        __syncthreads();
    }
    const int* inc = pp ? sB : sA;
    for (int i = tid; i < NBINS; i += 256) start[i] = inc[i] - cnt[i];
    __syncthreads();
#pragma unroll
    for (int k = 0; k < 16; k++) {
        if (rank[k] >= 0) {
            int b = rec[k].x >> 23;
            sorted[start[b] + rank[k]] = rec[k];
        }
    }
    __syncthreads();
    uint2* outp = E2 + (size_t)y * EE;
    for (int i = tid; i < m; i += 256) {
        uint2 r = sorted[i];
        int b = r.x >> 23;
        outp[gbase[b] + (i - start[b])] = r;
    }
}

// S4: per-bin counting sort -> compact CSR records (src u16 | w'=w*dinv[d] f16)
// + rowptr + dinv. Reads uint2 staging E2, writes 4B records to E1.
__launch_bounds__(256)
__global__ void sortbin_kernel(const uint2* __restrict__ E2, const int* __restrict__ chunkHist,
                               unsigned int* __restrict__ E1, int* __restrict__ rowptr,
                               float* __restrict__ dinvG, int batch) {
    __shared__ uint2 es[CAP];   // 48 KB
    __shared__ int cnt[BKT];
    __shared__ float wsm[BKT];
    __shared__ int cur[BKT];
    int b = blockIdx.x, y = blockIdx.y, tid = threadIdx.x;
    int t = batch * 6 + y;
    const uint2* gE = E2 + (size_t)y * EE;
    unsigned int* oE = E1 + (size_t)t * EE;
    const int* off = chunkHist + (size_t)t * NBINS * NCH;
    int e0 = off[b * NCH];
    int e1 = (b == NBINS - 1) ? EE : off[(b + 1) * NCH];
    int seg = e1 - e0;
    for (int i = tid; i < seg; i += 256) es[i] = gE[e0 + i];
    if (tid < BKT) { cnt[tid] = 0; wsm[tid] = 0.0f; }
    __syncthreads();
    for (int i = tid; i < seg; i += 256) {
        int dl = (es[i].x >> 16) & 127;
        atomicAdd(&cnt[dl], 1);
        atomicAdd(&wsm[dl], __uint_as_float(es[i].y));
    }
    __syncthreads();
    int ogv = (tid < BKT) ? cnt[tid] : 0;
    for (int o = 1; o < BKT; o <<= 1) {
        int u = (tid < BKT && tid >= o) ? cnt[tid - o] : 0;
        __syncthreads();
        if (tid < BKT) cnt[tid] += u;
        __syncthreads();
    }
    if (tid < BKT) {
        int exc = cnt[tid] - ogv;
        cur[tid] = exc;
        float dv = rsqrtf(1.0f + wsm[tid]);
        wsm[tid] = dv;   // reuse as dinv-local
        int node = b * BKT + tid;
        if (node <= NN) {
            rowptr[(size_t)t * RP + node] = e0 + exc;
            if (node < NN) dinvG[(size_t)t * NN + node] = dv;
        }
    }
    __syncthreads();
    for (int i = tid; i < seg; i += 256) {
        uint2 p = es[i];
        int dl = (p.x >> 16) & 127;
        int pos = atomicAdd(&cur[dl], 1);
        float wv = __uint_as_float(p.y) * wsm[dl];
        oE[e0 + pos] = (p.x & 0xFFFF) | ((unsigned int)f_to_h16(wv) << 16);
    }
}

// S4b: xs[t][n][f] = (f16)(dinv[t][n] * x[t][n][f])
__global__ void xs_kernel(const float* __restrict__ x, const float* __restrict__ dinvG,
                          _Float16* __restrict__ xs16) {
    int gid = blockIdx.x * 256 + threadIdx.x;   // TT*NN*4 float4 groups (exact: 9375 blocks)
    int tn = gid >> 2;
    float dd = dinvG[tn];
    float4 v = ((const float4*)x)[gid];
    _Float16 h[4] = {(_Float16)(dd * v.x), (_Float16)(dd * v.y),
                     (_Float16)(dd * v.z), (_Float16)(dd * v.w)};
    uint2 o;
    __builtin_memcpy(&o, h, 8);
    ((uint2*)xs16)[gid] = o;
}

// S5: CSR gather: wave per (t,node). 2-way software-pipelined edge loop.
__global__ void gather_csr(const unsigned int* __restrict__ E1, const int* __restrict__ rowptr,
                           const float* __restrict__ dinvG, const _Float16* __restrict__ xs16,
                           _Float16* __restrict__ xagg16) {
    int t = blockIdx.y;
    int n = blockIdx.x * 4 + (threadIdx.x >> 6);
    if (n >= NN) return;
    int lane = threadIdx.x & 63;
    int eo = lane >> 3, fp = lane & 7;
    const unsigned int* gE = E1 + (size_t)t * EE;
    const _Float16* xs = xs16 + (size_t)t * NN * FF;
    int r0 = rowptr[(size_t)t * RP + n], r1 = rowptr[(size_t)t * RP + n + 1];
    float a0 = 0.0f, a1 = 0.0f;
    int e = r0 + eo;
    for (; e + 8 < r1; e += 16) {
        unsigned int recA = gE[e];
        unsigned int recB = gE[e + 8];
        unsigned int xpA = *(const unsigned int*)(xs + (size_t)(recA & 0xFFFF) * FF + 2 * fp);
        unsigned int xpB = *(const unsigned int*)(xs + (size_t)(recB & 0xFFFF) * FF + 2 * fp);
        float wA = h16_to_f((unsigned short)(recA >> 16));
        float wB = h16_to_f((unsigned short)(recB >> 16));
        a0 += wA * h16_to_f((unsigned short)(xpA & 0xFFFF));
        a1 += wA * h16_to_f((unsigned short)(xpA >> 16));
        a0 += wB * h16_to_f((unsigned short)(xpB & 0xFFFF));
        a1 += wB * h16_to_f((unsigned short)(xpB >> 16));
    }
    if (e < r1) {
        unsigned int rec = gE[e];
        float wv = h16_to_f((unsigned short)(rec >> 16));
        unsigned int xp = *(const unsigned int*)(xs + (size_t)(rec & 0xFFFF) * FF + 2 * fp);
        a0 += wv * h16_to_f((unsigned short)(xp & 0xFFFF));
        a1 += wv * h16_to_f((unsigned short)(xp >> 16));
    }
    a0 += __shfl_xor(a0, 8);  a1 += __shfl_xor(a1, 8);
    a0 += __shfl_xor(a0, 16); a1 += __shfl_xor(a1, 16);
    a0 += __shfl_xor(a0, 32); a1 += __shfl_xor(a1, 32);
    if (eo == 0) {
        float dd = dinvG[(size_t)t * NN + n];
        unsigned int xp = *(const unsigned int*)(xs + (size_t)n * FF + 2 * fp);
        float o0 = a0 + dd * h16_to_f((unsigned short)(xp & 0xFFFF));
        float o1 = a1 + dd * h16_to_f((unsigned short)(xp >> 16));
        unsigned int pack = (unsigned int)f_to_h16(o0) | ((unsigned int)f_to_h16(o1) << 16);
        ((unsigned int*)(xagg16 + ((size_t)t * NN + n) * FF))[fp] = pack;
    }
}

// S6 (horizon): 3-feature CSR re-aggregation of predsc over t=11, 2-way MLP.
__global__ void gather3_csr(const unsigned int* __restrict__ E1, const int* __restrict__ rowptr,
                            const float* __restrict__ dinvG, const float* __restrict__ predsc,
                            _Float16* __restrict__ xaggH16) {
    int n = blockIdx.x * 4 + (threadIdx.x >> 6);
    if (n >= NN) return;
    int lane = threadIdx.x & 63;
    int eo = lane >> 2, f = lane & 3;
    const unsigned int* gE = E1 + (size_t)11 * EE;
    const float* dv = dinvG + (size_t)11 * NN;
    int r0 = rowptr[(size_t)11 * RP + n], r1 = rowptr[(size_t)11 * RP + n + 1];
    float acc = 0.0f;
    int e = r0 + eo;
    for (; e + 16 < r1; e += 32) {
        unsigned int recA = gE[e];
        unsigned int recB = gE[e + 16];
        if (f < 3) {
            float pA = predsc[(size_t)(recA & 0xFFFF) * 4 + f];
            float pB = predsc[(size_t)(recB & 0xFFFF) * 4 + f];
            acc += h16_to_f((unsigned short)(recA >> 16)) * pA;
            acc += h16_to_f((unsigned short)(recB >> 16)) * pB;
        }
    }
    if (e < r1) {
        unsigned int rec = gE[e];
        if (f < 3)
            acc += h16_to_f((unsigned short)(rec >> 16)) * predsc[(size_t)(rec & 0xFFFF) * 4 + f];
    }
    acc += __shfl_xor(acc, 4);
    acc += __shfl_xor(acc, 8);
    acc += __shfl_xor(acc, 16);
    acc += __shfl_xor(acc, 32);
    if (lane < 3) {
        float res = acc + dv[n] * predsc[(size_t)n * 4 + f];
        xaggH16[(size_t)n * FF + f] = (_Float16)res;
    }
}

// ---------------------------------------------------------------------------
// W: fold Wc into Wl_top -> BcatT[g][n=128][k: h(0..127) | x(128..143) | 0(144..159)]
__global__ void weight_kernel(const float* Wc0, const float* bc0, const float* Wl0, const float* bl0,
                              const float* Wc1, const float* bc1, const float* Wl1, const float* bl1,
                              const float* Wc2, const float* bc2, const float* Wl2, const float* bl2,
                              _Float16* __restrict__ BcatT, float* __restrict__ beff) {
    __shared__ float WcS[FF][HH];
    int g = blockIdx.x;
    int n = threadIdx.x;  // 128
    const float* Wc = g == 0 ? Wc0 : (g == 1 ? Wc1 : Wc2);
    const float* bc = g == 0 ? bc0 : (g == 1 ? bc1 : bc2);
    const float* Wl = g == 0 ? Wl0 : (g == 1 ? Wl1 : Wl2);
    const float* bl = g == 0 ? bl0 : (g == 1 ? bl1 : bl2);
    for (int q = 0; q < FF; q++) WcS[q][n] = Wc[q * HH + n];
    __syncthreads();
    float acc[FF];
#pragma unroll
    for (int i = 0; i < FF; i++) acc[i] = 0.0f;
    float accb = 0.0f;
    for (int k = 0; k < HH; k++) {
        float wl = Wl[k * HH + n];
        accb += bc[k] * wl;
#pragma unroll
        for (int i = 0; i < FF; i++) acc[i] += WcS[i][k] * wl;
    }
    _Float16* row = BcatT + ((size_t)g * HH + n) * BKROW;
    for (int j = 0; j < HH; j++) row[j] = (_Float16)Wl[(size_t)(HH + j) * HH + n];
#pragma unroll
    for (int i = 0; i < FF; i++) row[HH + i] = (_Float16)acc[i];
#pragma unroll
    for (int i = 144; i < 160; i++) row[i] = (_Float16)0.0f;
    beff[g * HH + n] = bl[n] + accb;
}

// ---------------------------------------------------------------------------
// CELLSEQ v5: fused multi-step GRU cell, transposed MFMA, 2 barriers/step.
//  - committed h lives in REGISTERS (hreg, 8 VGPR/lane: 4 nodes x 4 cols);
//  - LDS Hin[2] holds the PRE-MASKED next-step input (epilogue writes
//    hm[t+1] ? hreg : 0) -> no mask selects in phase A, no final copy loop;
//  - Ax double-buffered, staged early in phase B (latency hidden under MFMA);
//  - per step: [phase A: z/r MFMA + rescale->Ar] bar [phase B: issue next
//    staging, h~ MFMA, epilogue->Hin[next]/hio, commit Ax[next]] bar.
__launch_bounds__(512, 2)
__global__ void cellseq_kernel(const _Float16* __restrict__ xaggBase,
                               _Float16* __restrict__ hio,
                               const _Float16* __restrict__ BcatT,
                               const float* __restrict__ beff,
                               const unsigned char* __restrict__ hmAll,
                               const unsigned char* __restrict__ mcAll,
                               int nsteps) {
    __shared__ _Float16 Hin[2][64 * H_STR];   // 2 x 17408 B : pre-masked h input
    __shared__ _Float16 Ar[64 * AR_STR];      // 17408 B : rescaled h (h * sig(r))
    __shared__ _Float16 Ax[2][64 * AX_STR];   // 2 x 5120 B : x-part + zero pad
    const int tid = threadIdx.x;              // 0..511
    const int m0 = blockIdx.x * 64;
    const int lane = tid & 63;
    const int w = tid >> 6;                   // 0..7
    const int mrow = lane & 15;
    const int quad = lane >> 4;
    const int col0 = w * 16;
    const int cb = col0 + quad * 4;           // this lane's 4 output cols
    const bool rec = (hmAll != nullptr);

    // persistent per-lane biases (own 4 cols)
    const float4 bz4 = *(const float4*)(beff + cb);
    const float4 br4 = *(const float4*)(beff + HH + cb);
    const float4 bh4 = *(const float4*)(beff + 2 * HH + cb);

    // persistent weight fragments for ALL gates (A-operand rows = col0+mrow)
    const _Float16* Wzp = BcatT + (size_t)(col0 + mrow) * BKROW + quad * 8;
    half8_t wz[5], wr[5], wh[5];
#pragma unroll
    for (int ks = 0; ks < 5; ks++) {
        wz[ks] = *(const half8_t*)(Wzp + ks * 32);
        wr[ks] = *(const half8_t*)(Wzp + (size_t)HH * BKROW + ks * 32);
        wh[ks] = *(const half8_t*)(Wzp + (size_t)2 * HH * BKROW + ks * 32);
    }

    // ---- prologue: zero Ax pads (both buffers), stage Ax[0], init Hin[0] ----
    for (int idx = tid; idx < 256; idx += 512) {
        int buf = idx >> 7, r2 = idx & 127;
        int row = r2 >> 1, q = r2 & 1;
        *(uint4*)(Ax[buf] + row * AX_STR + 16 + q * 8) = make_uint4(0, 0, 0, 0);
    }
    for (int idx = tid; idx < 128; idx += 512) {
        int row = idx >> 1, q = idx & 1;
        int g = m0 + row;
        uint4 v = make_uint4(0, 0, 0, 0);
        if (g < NN) v = *(const uint4*)(xaggBase + (size_t)g * FF + q * 8);
        *(uint4*)(Ax[0] + row * AX_STR + q * 8) = v;
    }
    for (int idx = tid; idx < 1024; idx += 512) {
        int row = idx >> 4, q = idx & 15;
        int g = m0 + row;
        uint4 v = make_uint4(0, 0, 0, 0);
        if (!rec && g < NN) v = *(const uint4*)(hio + (size_t)g * HH + q * 8);
        *(uint4*)(Hin[0] + row * H_STR + q * 8) = v;
    }
    uint2 hreg[4];
#pragma unroll
    for (int nt = 0; nt < 4; nt++) hreg[nt] = make_uint2(0, 0);
    __syncthreads();

    int cur = 0;
    for (int t = 0; t < nsteps; t++) {
        const _Float16* Hc = Hin[cur];
        const _Float16* Axc = Ax[cur];

        // ---- phase A: z/r MFMAs from pre-masked Hc, rescale -> Ar ----
        floatx4 zacc[4];
        uint2 hpv[4];   // masked hprev (own 4 cols per node-tile)
#pragma unroll
        for (int nt = 0; nt < 4; nt++) {
            int node = nt * 16 + mrow;
            const _Float16* hp = Hc + node * H_STR;
            half8_t hx[5];
#pragma unroll
            for (int ks = 0; ks < 4; ks++) hx[ks] = *(const half8_t*)(hp + ks * 32 + quad * 8);
            hx[4] = *(const half8_t*)(Axc + node * AX_STR + quad * 8);
            floatx4 za = {0.0f, 0.0f, 0.0f, 0.0f}, ra = {0.0f, 0.0f, 0.0f, 0.0f};
#pragma unroll
            for (int ks = 0; ks < 5; ks++)
                za = __builtin_amdgcn_mfma_f32_16x16x32_f16(wz[ks], hx[ks], za, 0, 0, 0);
#pragma unroll
            for (int ks = 0; ks < 5; ks++)
                ra = __builtin_amdgcn_mfma_f32_16x16x32_f16(wr[ks], hx[ks], ra, 0, 0, 0);
            zacc[nt] = za;
            uint2 hp2 = *(const uint2*)(hp + cb);   // already masked
            hpv[nt] = hp2;
            float r0 = fsig(ra[0] + br4.x), r1 = fsig(ra[1] + br4.y);
            float r2 = fsig(ra[2] + br4.z), r3 = fsig(ra[3] + br4.w);
            float hp0 = h16_to_f((unsigned short)(hp2.x & 0xFFFF));
            float hp1 = h16_to_f((unsigned short)(hp2.x >> 16));
            float hp2f = h16_to_f((unsigned short)(hp2.y & 0xFFFF));
            float hp3 = h16_to_f((unsigned short)(hp2.y >> 16));
            uint2 o;
            o.x = (unsigned int)f_to_h16(hp0 * r0) | ((unsigned int)f_to_h16(hp1 * r1) << 16);
            o.y = (unsigned int)f_to_h16(hp2f * r2) | ((unsigned int)f_to_h16(hp3 * r3) << 16);
            *(uint2*)(Ar + node * AR_STR + cb) = o;
        }
        __syncthreads();   // bar A: Ar complete; Hc/Axc reads of phase A done

        // ---- phase B: early-issue next staging, h~ MFMAs, epilogue ----
        const bool hasNext = (t + 1 < nsteps);
        // early global loads: next Ax slice (1 uint4 for tid<128)
        uint4 axn = make_uint4(0, 0, 0, 0);
        if (hasNext && tid < 128) {
            int row = tid >> 1, q = tid & 1;
            int g = m0 + row;
            if (g < NN)
                axn = *(const uint4*)(xaggBase + (size_t)(t + 1) * NN * FF + (size_t)g * FF + q * 8);
        }
        // early byte loads: mc[t], hm[t+1]
        bool mcb[4], hmb[4];
#pragma unroll
        for (int nt = 0; nt < 4; nt++) {
            int g = m0 + nt * 16 + mrow;
            mcb[nt] = false; hmb[nt] = false;
            if (rec && g < NN) {
                mcb[nt] = mcAll[(size_t)t * NN + g] != 0;
                if (hasNext) hmb[nt] = hmAll[(size_t)(t + 1) * NN + g] != 0;
            }
        }
#pragma unroll
        for (int nt = 0; nt < 4; nt++) {
            int node = nt * 16 + mrow;
            const _Float16* ap = Ar + node * AR_STR;
            half8_t hx[5];
#pragma unroll
            for (int ks = 0; ks < 4; ks++) hx[ks] = *(const half8_t*)(ap + ks * 32 + quad * 8);
            hx[4] = *(const half8_t*)(Axc + node * AX_STR + quad * 8);
            floatx4 ha = {0.0f, 0.0f, 0.0f, 0.0f};
#pragma unroll
            for (int ks = 0; ks < 5; ks++)
                ha = __builtin_amdgcn_mfma_f32_16x16x32_f16(wh[ks], hx[ks], ha, 0, 0, 0);
            int g = m0 + node;
            float z0 = fsig(zacc[nt][0] + bz4.x), z1 = fsig(zacc[nt][1] + bz4.y);
            float z2 = fsig(zacc[nt][2] + bz4.z), z3 = fsig(zacc[nt][3] + bz4.w);
            float t0 = ftanh(ha[0] + bh4.x), t1 = ftanh(ha[1] + bh4.y);
            float t2 = ftanh(ha[2] + bh4.z), t3 = ftanh(ha[3] + bh4.w);
            float hp0 = h16_to_f((unsigned short)(hpv[nt].x & 0xFFFF));
            float hp1 = h16_to_f((unsigned short)(hpv[nt].x >> 16));
            float hp2 = h16_to_f((unsigned short)(hpv[nt].y & 0xFFFF));
            float hp3 = h16_to_f((unsigned short)(hpv[nt].y >> 16));
            float n0 = z0 * hp0 + (1.0f - z0) * t0;
            float n1 = z1 * hp1 + (1.0f - z1) * t1;
            float n2 = z2 * hp2 + (1.0f - z2) * t2;
            float n3 = z3 * hp3 + (1.0f - z3) * t3;
            uint2 o;
            o.x = (unsigned int)f_to_h16(n0) | ((unsigned int)f_to_h16(n1) << 16);
            o.y = (unsigned int)f_to_h16(n2) | ((unsigned int)f_to_h16(n3) << 16);
            if (rec) {
                // commit to register state, then emit pre-masked next input
                if (mcb[nt]) hreg[nt] = o;
                uint2 wv = (hasNext && hmb[nt]) ? hreg[nt] : make_uint2(0, 0);
                if (hasNext) {
                    *(uint2*)(Hin[cur ^ 1] + node * H_STR + cb) = wv;
                } else if (g < NN) {
                    // last step: hio = mc[last] ? hreg : 0  (fused prep_hp)
                    uint2 fv = mcb[nt] ? hreg[nt] : make_uint2(0, 0);
                    *(uint2*)(hio + (size_t)g * HH + cb) = fv;
                }
            } else if (g < NN) {
                *(uint2*)(hio + (size_t)g * HH + cb) = o;
            }
        }
        // commit next Ax slice to LDS
        if (hasNext && tid < 128) {
            int row = tid >> 1, q = tid & 1;
            *(uint4*)(Ax[cur ^ 1] + row * AX_STR + q * 8) = axn;
        }
        __syncthreads();   // bar B: Hin[next]/Ax[next] ready; Ar readers done
        cur ^= 1;
    }
}

// C4: out[n][o] = h . head_W[:,o] + head_b[o]; also predsc[n][o] = dinv11[n]*out
__global__ void head_kernel(const _Float16* __restrict__ hp, const float* __restrict__ headW,
                            const float* __restrict__ headb, const float* __restrict__ dinv11,
                            float* __restrict__ out, float* __restrict__ predsc) {
    int node = (blockIdx.x * 256 + threadIdx.x) >> 6;
    int lane = threadIdx.x & 63;
    if (node >= NN) return;
    const _Float16* h = hp + (size_t)node * HH;
    float h0 = (float)h[lane], h1 = (float)h[64 + lane];
    float s0 = h0 * headW[lane * 3 + 0] + h1 * headW[(64 + lane) * 3 + 0];
    float s1 = h0 * headW[lane * 3 + 1] + h1 * headW[(64 + lane) * 3 + 1];
    float s2 = h0 * headW[lane * 3 + 2] + h1 * headW[(64 + lane) * 3 + 2];
#pragma unroll
    for (int off = 32; off > 0; off >>= 1) {
        s0 += __shfl_down(s0, off);
        s1 += __shfl_down(s1, off);
        s2 += __shfl_down(s2, off);
    }
    if (lane == 0) {
        float o0 = s0 + headb[0], o1 = s1 + headb[1], o2 = s2 + headb[2];
        out[(size_t)node * 3 + 0] = o0;
        out[(size_t)node * 3 + 1] = o1;
        out[(size_t)node * 3 + 2] = o2;
        float dd = dinv11[node];
        predsc[(size_t)node * 4 + 0] = dd * o0;
        predsc[(size_t)node * 4 + 1] = dd * o1;
        predsc[(size_t)node * 4 + 2] = dd * o2;
    }
}

extern "C" void kernel_launch(void* const* d_in, const int* in_sizes, int n_in,
                              void* d_out, int out_size, void* d_ws, size_t ws_size,
                              hipStream_t stream) {
    const float* x = (const float*)d_in[0];
    const int* ei = (const int*)d_in[1];
    const float* ea = (const float*)d_in[2];
    const void* mask = d_in[3];
    const float* Wc[3] = {(const float*)d_in[4], (const float*)d_in[8], (const float*)d_in[12]};
    const float* bc[3] = {(const float*)d_in[5], (const float*)d_in[9], (const float*)d_in[13]};
    const float* Wl[3] = {(const float*)d_in[6], (const float*)d_in[10], (const float*)d_in[14]};
    const float* bl[3] = {(const float*)d_in[7], (const float*)d_in[11], (const float*)d_in[15]};
    const float* headW = (const float*)d_in[16];
    const float* headb = (const float*)d_in[17];
    float* out = (float*)d_out;

    char* w = (char*)d_ws;
    auto alloc = [&](size_t bytes) {
        char* p = w;
        w += (bytes + 255) & ~(size_t)255;
        return p;
    };
    float* dinv = (float*)alloc((size_t)TT * NN * 4);
    _Float16* xagg16 = (_Float16*)alloc((size_t)TT * NN * FF * 2);
    _Float16* xaggH16 = (_Float16*)alloc((size_t)NN * FF * 2);
    _Float16* xs16 = (_Float16*)alloc((size_t)TT * NN * FF * 2);
    int* chunkHist = (int*)alloc((size_t)TT * NBINS * NCH * 4);
    int* rowptr = (int*)alloc((size_t)TT * RP * 4);
    unsigned int* E1 = (unsigned int*)alloc((size_t)TT * EE * 4);  // compact CSR records
    uint2* E2 = (uint2*)alloc((size_t)6 * EE * 8);                 // staging, 6 slots (2 batches)
    _Float16* BcatT = (_Float16*)alloc((size_t)3 * HH * BKROW * 2);
    float* beff = (float*)alloc(3 * HH * 4);
    float* predsc = (float*)alloc((size_t)NN * 4 * 4);
    unsigned char* hm = (unsigned char*)alloc((size_t)TT * NN);
    unsigned char* mc = (unsigned char*)alloc((size_t)TT * NN);
    int* flag = (int*)alloc(64);

    // f16 horizon hidden state aliases the E2 staging area (dead after sortbin).
    _Float16* hph = (_Float16*)E2;   // 12.8 MB

    detect_mask<<<1, 256, 0, stream>>>((const unsigned char*)mask, flag);
    build_masks<<<(NN + 255) / 256, 256, 0, stream>>>(mask, flag, hm, mc);

    hist_kernel<<<dim3(NCH, TT), 256, 0, stream>>>(ei, chunkHist);
    scan_kernel<<<TT, 1024, 0, stream>>>(chunkHist);
    for (int b = 0; b < 2; b++) {
        scatter_kernel<<<dim3(NCH, 6), 256, 0, stream>>>(ei, ea, chunkHist, E2, b);
        sortbin_kernel<<<dim3(NBINS, 6), 256, 0, stream>>>(E2, chunkHist, E1, rowptr, dinv, b);
    }
    xs_kernel<<<TT * NN * 4 / 256, 256, 0, stream>>>(x, dinv, xs16);
    gather_csr<<<dim3((NN + 3) / 4, TT), 256, 0, stream>>>(E1, rowptr, dinv, xs16, xagg16);

    weight_kernel<<<3, 128, 0, stream>>>(Wc[0], bc[0], Wl[0], bl[0],
                                         Wc[1], bc[1], Wl[1], bl[1],
                                         Wc[2], bc[2], Wl[2], bl[2], BcatT, beff);

    // fused recurrent chain t=0..11: h resident in regs/LDS, writes hph = mc11 ? h : 0
    cellseq_kernel<<<CGB, 512, 0, stream>>>(xagg16, hph, BcatT, beff, hm, mc, TT);

    hipMemcpyAsync(xaggH16, xagg16 + (size_t)11 * NN * FF, (size_t)NN * FF * 2,
                   hipMemcpyDeviceToDevice, stream);

    for (int k = 0; k < 6; k++) {
        const _Float16* xa = (k == 0) ? (xagg16 + (size_t)11 * NN * FF) : xaggH16;
        cellseq_kernel<<<CGB, 512, 0, stream>>>(xa, hph, BcatT, beff, nullptr, nullptr, 1);
        head_kernel<<<NN * 64 / 256, 256, 0, stream>>>(hph, headW, headb, dinv + (size_t)11 * NN,
                                                       out + (size_t)k * NN * 3, predsc);
        if (k < 5) {
            gather3_csr<<<(NN + 3) / 4, 256, 0, stream>>>(E1, rowptr, dinv, predsc, xaggH16);
        }
    }
}